// Round 3
// baseline (469.916 us; speedup 1.0000x reference)
//
#include <hip/hip_runtime.h>
#include <hip/hip_bf16.h>

#define NN 50000
#define EE 400000
#define REPS 16

__device__ inline unsigned bf16pair(float a, float b) {
    unsigned ua = __float_as_uint(a), ub = __float_as_uint(b);
    ua = (ua + 0x7FFFu + ((ua >> 16) & 1u)) >> 16;
    ub = (ub + 0x7FFFu + ((ub >> 16) & 1u)) >> 16;
    return ua | (ub << 16);
}

// ---------------- small prep: fold a-vectors through W ----------------
__global__ void prep_vectors(const float* __restrict__ W_node, const float* __restrict__ W_edge,
                             const float* __restrict__ a_node, const float* __restrict__ a_edge,
                             float* wn_a1, float* wn_a2, float* wn_e1, float* we_a2) {
    int t = threadIdx.x;
    if (t < 256) {
        float x1 = 0.f, x2 = 0.f, x3 = 0.f;
        for (int j = 0; j < 128; ++j) {
            float w = W_node[t * 128 + j];
            x1 += w * a_node[j];
            x2 += w * a_node[128 + j];
            x3 += w * a_edge[j];
        }
        wn_a1[t] = x1; wn_a2[t] = x2; wn_e1[t] = x3;
    }
    if (t < 128) {
        float x = 0.f;
        for (int j = 0; j < 128; ++j) x += W_edge[t * 128 + j] * a_edge[128 + j];
        we_a2[t] = x;
    }
}

// ---------------- tiled f32 GEMM -> bf16 interleaved hev ----------------
template <int K, int OFFH>
__global__ __launch_bounds__(256) void gemm_f32(const float* __restrict__ A, const float* __restrict__ B,
                                                unsigned* __restrict__ hevu, int M) {
    constexpr int BM = 64, BK = 32;
    __shared__ float Ast[BK][BM];     // transposed A tile
    __shared__ float Bs[BK][128];
    int t = threadIdx.x;
    int bm = blockIdx.x * BM;
    int tx = t & 15, ty = t >> 4;     // tx: 8-col group, ty: 4-row group
    float acc[4][8] = {};
    for (int k0 = 0; k0 < K; k0 += BK) {
        for (int c = t; c < BM * BK / 4; c += 256) {
            int row = c >> 3, pos = (c & 7) << 2;
            float4 v = make_float4(0.f, 0.f, 0.f, 0.f);
            int gr = bm + row;
            if (gr < M) v = *reinterpret_cast<const float4*>(A + (size_t)gr * K + k0 + pos);
            Ast[pos + 0][row] = v.x; Ast[pos + 1][row] = v.y;
            Ast[pos + 2][row] = v.z; Ast[pos + 3][row] = v.w;
        }
        for (int c = t; c < BK * 128 / 4; c += 256) {
            int row = c >> 5, pos = (c & 31) << 2;
            *reinterpret_cast<float4*>(&Bs[row][pos]) =
                *reinterpret_cast<const float4*>(B + (size_t)(k0 + row) * 128 + pos);
        }
        __syncthreads();
#pragma unroll
        for (int kk = 0; kk < BK; ++kk) {
            float4 a = *reinterpret_cast<const float4*>(&Ast[kk][ty * 4]);
            float4 b0 = *reinterpret_cast<const float4*>(&Bs[kk][tx * 8]);
            float4 b1 = *reinterpret_cast<const float4*>(&Bs[kk][tx * 8 + 4]);
            const float* av = reinterpret_cast<const float*>(&a);
            const float* bv0 = reinterpret_cast<const float*>(&b0);
            const float* bv1 = reinterpret_cast<const float*>(&b1);
#pragma unroll
            for (int r = 0; r < 4; ++r) {
#pragma unroll
                for (int c = 0; c < 4; ++c) {
                    acc[r][c] += av[r] * bv0[c];
                    acc[r][c + 4] += av[r] * bv1[c];
                }
            }
        }
        __syncthreads();
    }
#pragma unroll
    for (int r = 0; r < 4; ++r) {
        int gr = bm + ty * 4 + r;
        if (gr < M) {
            unsigned* rowp = hevu + (size_t)gr * 128;
#pragma unroll
            for (int p = 0; p < 4; ++p) {
                rowp[((tx * 4 + p) << 1) + OFFH] = bf16pair(acc[r][2 * p], acc[r][2 * p + 1]);
            }
        }
    }
}

// ---------------- per-node scalars s1,s2,t1 (wave per row, K=256) ----------------
__global__ void node_scalars(const float* __restrict__ NF, const float* __restrict__ w1,
                             const float* __restrict__ w2, const float* __restrict__ w3,
                             float* __restrict__ s1, float* __restrict__ s2, float* __restrict__ t1) {
    int wave = (int)((blockIdx.x * (size_t)blockDim.x + threadIdx.x) >> 6);
    int lane = threadIdx.x & 63;
    if (wave >= NN) return;
    const float* row = NF + (size_t)wave * 256;
    float4 v = *reinterpret_cast<const float4*>(row + lane * 4);
    float a = 0.f, b = 0.f, c = 0.f;
    const float* x = reinterpret_cast<const float*>(&v);
#pragma unroll
    for (int j = 0; j < 4; ++j) {
        a += x[j] * w1[lane * 4 + j];
        b += x[j] * w2[lane * 4 + j];
        c += x[j] * w3[lane * 4 + j];
    }
    for (int off = 32; off; off >>= 1) {
        a += __shfl_down(a, off);
        b += __shfl_down(b, off);
        c += __shfl_down(c, off);
    }
    if (lane == 0) { s1[wave] = a; s2[wave] = b; t1[wave] = c; }
}

// ---------------- per-edge scalar t2e (wave per row, K=128) ----------------
__global__ void edge_scalar(const float* __restrict__ EF, const float* __restrict__ w,
                            float* __restrict__ t2e) {
    int wave = (int)((blockIdx.x * (size_t)blockDim.x + threadIdx.x) >> 6);
    int lane = threadIdx.x & 63;
    if (wave >= EE) return;
    float2 v = *reinterpret_cast<const float2*>(EF + (size_t)wave * 128 + lane * 2);
    float a = v.x * w[lane * 2] + v.y * w[lane * 2 + 1];
    for (int off = 32; off; off >>= 1) a += __shfl_down(a, off);
    if (lane == 0) t2e[wave] = a;
}

// ---------------- per-edge attention + replicated segment sums ----------------
__global__ void attention(const int* __restrict__ edges, const float* __restrict__ s1,
                          const float* __restrict__ s2, const float* __restrict__ t1,
                          const float* __restrict__ t2e, float* __restrict__ natt,
                          float* __restrict__ eatt, float* __restrict__ nsumR,
                          float* __restrict__ esumR, int* __restrict__ countsR) {
    int i = blockIdx.x * blockDim.x + threadIdx.x;
    if (i >= 2 * EE) return;
    int rep = blockIdx.x & (REPS - 1);
    int s, d, j;
    if (i < EE) { j = i; int2 p = *reinterpret_cast<const int2*>(edges + 2 * j); s = p.x; d = p.y; }
    else        { j = i - EE; int2 p = *reinterpret_cast<const int2*>(edges + 2 * j); s = p.y; d = p.x; }
    float xn = s1[s] + s2[d];
    xn = xn >= 0.f ? xn : 0.2f * xn;
    xn = fminf(fmaxf(xn, -2.f), 2.f);
    float na = expf(xn);
    float xe = t1[s] + t2e[j];
    xe = xe >= 0.f ? xe : 0.2f * xe;
    xe = fminf(fmaxf(xe, -2.f), 2.f);
    float ea = expf(xe);
    natt[i] = na; eatt[i] = ea;
    size_t base = (size_t)rep * NN + s;
    atomicAdd(&nsumR[base], na);
    atomicAdd(&esumR[base], ea);
    atomicAdd(&countsR[base], 1);
}

// ---------------- fold replicas ----------------
__global__ void reduce_reps(const float* __restrict__ nsumR, const float* __restrict__ esumR,
                            const int* __restrict__ countsR, float* __restrict__ nsum,
                            float* __restrict__ esum, int* __restrict__ counts) {
    int n = blockIdx.x * blockDim.x + threadIdx.x;
    if (n >= NN) return;
    float a = 0.f, b = 0.f; int c = 0;
    for (int g = 0; g < REPS; ++g) {
        a += nsumR[(size_t)g * NN + n];
        b += esumR[(size_t)g * NN + n];
        c += countsR[(size_t)g * NN + n];
    }
    nsum[n] = a; esum[n] = b; counts[n] = c;
}

// ---------------- scan: counts -> offsets (exclusive) ----------------
#define SCAN_CHUNK 2048
__global__ void scan_block_sums(const int* __restrict__ counts, int* __restrict__ bsums) {
    __shared__ int sdata[256];
    int b = blockIdx.x, t = threadIdx.x;
    int base = b * SCAN_CHUNK + t * 8;
    int s = 0;
    for (int j = 0; j < 8; ++j) { int idx = base + j; if (idx < NN) s += counts[idx]; }
    sdata[t] = s; __syncthreads();
    for (int off = 128; off; off >>= 1) { if (t < off) sdata[t] += sdata[t + off]; __syncthreads(); }
    if (t == 0) bsums[b] = sdata[0];
}
__global__ void scan_bsums(int* __restrict__ bsums, int nb) {
    if (threadIdx.x == 0 && blockIdx.x == 0) {
        int run = 0;
        for (int i = 0; i < nb; ++i) { int v = bsums[i]; bsums[i] = run; run += v; }
    }
}
__global__ void scan_final(const int* __restrict__ counts, const int* __restrict__ bsums,
                           int* __restrict__ offsets) {
    __shared__ int sdata[256];
    int b = blockIdx.x, t = threadIdx.x;
    int base = b * SCAN_CHUNK + t * 8;
    int loc[8]; int s = 0;
    for (int j = 0; j < 8; ++j) { int idx = base + j; int v = (idx < NN) ? counts[idx] : 0; loc[j] = v; s += v; }
    sdata[t] = s; __syncthreads();
    for (int off = 1; off < 256; off <<= 1) {
        int v = (t >= off) ? sdata[t - off] : 0;
        __syncthreads();
        sdata[t] += v;
        __syncthreads();
    }
    int run = sdata[t] - s + bsums[b];
    for (int j = 0; j < 8; ++j) {
        int idx = base + j;
        if (idx < NN) { offsets[idx] = run; run += loc[j]; }
    }
}

// ---------------- per-replica cursors from replica counts ----------------
__global__ void make_cursorR(const int* __restrict__ countsR, const int* __restrict__ offsets,
                             int* __restrict__ cursorR) {
    int n = blockIdx.x * blockDim.x + threadIdx.x;
    if (n >= NN) return;
    int run = offsets[n];
    for (int g = 0; g < REPS; ++g) {
        cursorR[(size_t)g * NN + n] = run;
        run += countsR[(size_t)g * NN + n];
    }
}

// ---------------- fill position->node map g ----------------
__global__ void fill_g(const int* __restrict__ offsets, const int* __restrict__ counts,
                       int* __restrict__ g) {
    int n = blockIdx.x * blockDim.x + threadIdx.x;
    if (n >= NN) return;
    int o = offsets[n], c = counts[n];
    for (int k = 0; k < c; ++k) g[o + k] = n;
}

// ---------------- normalize + CSR meta scatter (replicated cursors) + variance ----------------
__global__ void normalize_var(const float* __restrict__ natt, const float* __restrict__ eatt,
                              const float* __restrict__ nsum, const float* __restrict__ esum,
                              const int* __restrict__ g, const int* __restrict__ edges,
                              int* __restrict__ cursorR, float4* __restrict__ meta,
                              double* __restrict__ acc) {
    int i = blockIdx.x * blockDim.x + threadIdx.x;
    float nn = 0.f, en = 0.f;
    if (i < 2 * EE) {
        int gi = g[i];
        nn = natt[i] / nsum[gi];
        en = eatt[i] / esum[gi];
        int s, d;
        if (i < EE) { int2 p = *reinterpret_cast<const int2*>(edges + 2 * i); s = p.x; d = p.y; }
        else        { int2 p = *reinterpret_cast<const int2*>(edges + 2 * (i - EE)); s = p.y; d = p.x; }
        int rep = (i >> 8) & (REPS - 1);   // must match attention's block->rep mapping
        int p = atomicAdd(&cursorR[(size_t)rep * NN + s], 1);
        meta[p] = make_float4(__int_as_float(d), nn, en, 0.f);
    }
    double v[4] = { (double)nn, (double)nn * nn, (double)en, (double)en * en };
    __shared__ double sd[4][4];
    int lane = threadIdx.x & 63, wv = threadIdx.x >> 6;
#pragma unroll
    for (int q = 0; q < 4; ++q) {
        double x = v[q];
        for (int off = 32; off; off >>= 1) x += __shfl_down(x, off);
        if (lane == 0) sd[q][wv] = x;
    }
    __syncthreads();
    if (threadIdx.x < 4) {
        double x = sd[threadIdx.x][0] + sd[threadIdx.x][1] + sd[threadIdx.x][2] + sd[threadIdx.x][3];
        atomicAdd(&acc[threadIdx.x], x);
    }
}

// ---------------- CSR accumulate: wave per node, bf16 hev gathers ----------------
__global__ void accumulate(const float4* __restrict__ meta, const int* __restrict__ offsets,
                           const int* __restrict__ counts, const uint2* __restrict__ hev,
                           float* __restrict__ node_out, float* __restrict__ edge_out) {
    int wave = (int)((blockIdx.x * (size_t)blockDim.x + threadIdx.x) >> 6);
    int lane = threadIdx.x & 63;
    if (wave >= NN) return;
    int o = offsets[wave], c = counts[wave];
    float aH0 = 0.f, aH1 = 0.f, aE0 = 0.f, aE1 = 0.f;
    float4 m0 = make_float4(0.f, 0.f, 0.f, 0.f), m1 = m0;
    if (c > 0) m0 = meta[o];
    if (c > 1) m1 = meta[o + 1];
    for (int k = 0; k < c; ++k) {
        float4 mnext = (k + 2 < c) ? meta[o + k + 2] : m1;
        int d = __float_as_int(m0.x);
        uint2 v = hev[(size_t)d * 64 + lane];
        float h0 = __uint_as_float(v.x << 16);
        float h1 = __uint_as_float(v.x & 0xFFFF0000u);
        float e0 = __uint_as_float(v.y << 16);
        float e1 = __uint_as_float(v.y & 0xFFFF0000u);
        aH0 += h0 * m0.y; aH1 += h1 * m0.y;
        aE0 += e0 * m0.z; aE1 += e1 * m0.z;
        m0 = m1; m1 = mnext;
    }
    float2 rn = { aH0, aH1 }, re = { aE0, aE1 };
    *reinterpret_cast<float2*>(node_out + (size_t)wave * 128 + lane * 2) = rn;
    *reinterpret_cast<float2*>(edge_out + (size_t)wave * 128 + lane * 2) = re;
}

// ---------------- finalize variance ----------------
__global__ void finalize_var(const double* __restrict__ acc, float* __restrict__ out_var) {
    if (threadIdx.x == 0 && blockIdx.x == 0) {
        double M = 2.0 * EE;
        double nv = (acc[1] - acc[0] * acc[0] / M) / (M - 1.0);
        double ev = (acc[3] - acc[2] * acc[2] / M) / (M - 1.0);
        out_var[0] = (float)nv;
        out_var[1] = (float)ev;
    }
}

extern "C" void kernel_launch(void* const* d_in, const int* in_sizes, int n_in,
                              void* d_out, int out_size, void* d_ws, size_t ws_size,
                              hipStream_t stream) {
    const float* node_fts = (const float*)d_in[0];
    const float* edge_fts = (const float*)d_in[1];
    const int*   edges    = (const int*)d_in[2];
    const float* W_node   = (const float*)d_in[3];
    const float* W_edge   = (const float*)d_in[4];
    const float* a_node   = (const float*)d_in[5];
    const float* a_edge   = (const float*)d_in[6];
    float* out = (float*)d_out;

    char* w = (char*)d_ws;
    auto alloc = [&](size_t bytes) -> void* {
        void* p = (void*)w;
        w += (bytes + 255) & ~(size_t)255;
        return p;
    };
    unsigned* hevu = (unsigned*)alloc((size_t)NN * 512);        // bf16 interleaved h/e rows
    float* s1    = (float*)alloc(NN * 4);
    float* s2    = (float*)alloc(NN * 4);
    float* t1    = (float*)alloc(NN * 4);
    float* t2e   = (float*)alloc(EE * 4);
    float* natt  = (float*)alloc(2 * EE * 4);
    float* eatt  = (float*)alloc(2 * EE * 4);
    float4* meta = (float4*)alloc((size_t)2 * EE * 16);
    int*   offsets = (int*)alloc((NN + 1) * 4);
    int*   g       = (int*)alloc(2 * EE * 4);
    int*   bsums   = (int*)alloc(64 * 4);
    float* wn_a1 = (float*)alloc(256 * 4);
    float* wn_a2 = (float*)alloc(256 * 4);
    float* wn_e1 = (float*)alloc(256 * 4);
    float* we_a2 = (float*)alloc(128 * 4);
    float* nsum   = (float*)alloc(NN * 4);
    float* esum   = (float*)alloc(NN * 4);
    int*   counts = (int*)alloc(NN * 4);
    int*   cursorR = (int*)alloc((size_t)REPS * NN * 4);
    // contiguous zero block: nsumR, esumR (floats), countsR (ints), acc (4 doubles)
    char* zb = (char*)alloc((size_t)REPS * NN * 12 + 64);
    float* nsumR = (float*)zb;
    float* esumR = (float*)(zb + (size_t)REPS * NN * 4);
    int*   countsR = (int*)(zb + (size_t)REPS * NN * 8);
    double* acc = (double*)(zb + (size_t)REPS * NN * 12);

    hipMemsetAsync(zb, 0, (size_t)REPS * NN * 12 + 64, stream);

    prep_vectors<<<1, 256, 0, stream>>>(W_node, W_edge, a_node, a_edge, wn_a1, wn_a2, wn_e1, we_a2);

    const int gemm_grid = (NN + 63) / 64;  // 782
    gemm_f32<256, 0><<<gemm_grid, 256, 0, stream>>>(node_fts, W_node, hevu, NN);
    gemm_f32<128, 1><<<gemm_grid, 256, 0, stream>>>(edge_fts, W_edge, hevu, NN);

    node_scalars<<<(NN + 3) / 4, 256, 0, stream>>>(node_fts, wn_a1, wn_a2, wn_e1, s1, s2, t1);
    edge_scalar<<<(EE + 3) / 4, 256, 0, stream>>>(edge_fts, we_a2, t2e);

    attention<<<(2 * EE + 255) / 256, 256, 0, stream>>>(edges, s1, s2, t1, t2e, natt, eatt,
                                                        nsumR, esumR, countsR);

    reduce_reps<<<(NN + 255) / 256, 256, 0, stream>>>(nsumR, esumR, countsR, nsum, esum, counts);

    const int nscan = (NN + SCAN_CHUNK - 1) / SCAN_CHUNK;  // 25
    scan_block_sums<<<nscan, 256, 0, stream>>>(counts, bsums);
    scan_bsums<<<1, 64, 0, stream>>>(bsums, nscan);
    scan_final<<<nscan, 256, 0, stream>>>(counts, bsums, offsets);

    make_cursorR<<<(NN + 255) / 256, 256, 0, stream>>>(countsR, offsets, cursorR);
    fill_g<<<(NN + 255) / 256, 256, 0, stream>>>(offsets, counts, g);

    normalize_var<<<(2 * EE + 255) / 256, 256, 0, stream>>>(natt, eatt, nsum, esum, g, edges,
                                                            cursorR, meta, acc);

    accumulate<<<(NN + 3) / 4, 256, 0, stream>>>(meta, offsets, counts, (const uint2*)hevu,
                                                 out, out + (size_t)NN * 128);

    finalize_var<<<1, 64, 0, stream>>>(acc, out + (size_t)2 * NN * 128);
}

// Round 4
// 405.769 us; speedup vs baseline: 1.1581x; 1.1581x over previous
//
#include <hip/hip_runtime.h>
#include <hip/hip_bf16.h>

#define NN 50000
#define EE 400000
#define REPS 16
#define QSCALE 131072.0f   // 2^17 fixed-point scale for packed histogram

__device__ inline unsigned bf16pair(float a, float b) {
    unsigned ua = __float_as_uint(a), ub = __float_as_uint(b);
    ua = (ua + 0x7FFFu + ((ua >> 16) & 1u)) >> 16;
    ub = (ub + 0x7FFFu + ((ub >> 16) & 1u)) >> 16;
    return ua | (ub << 16);
}

// ---------------- small prep: fold a-vectors through W ----------------
__global__ void prep_vectors(const float* __restrict__ W_node, const float* __restrict__ W_edge,
                             const float* __restrict__ a_node, const float* __restrict__ a_edge,
                             float* wn_a1, float* wn_a2, float* wn_e1, float* we_a2) {
    int t = threadIdx.x;
    if (t < 256) {
        float x1 = 0.f, x2 = 0.f, x3 = 0.f;
        for (int j = 0; j < 128; ++j) {
            float w = W_node[t * 128 + j];
            x1 += w * a_node[j];
            x2 += w * a_node[128 + j];
            x3 += w * a_edge[j];
        }
        wn_a1[t] = x1; wn_a2[t] = x2; wn_e1[t] = x3;
    }
    if (t < 128) {
        float x = 0.f;
        for (int j = 0; j < 128; ++j) x += W_edge[t * 128 + j] * a_edge[128 + j];
        we_a2[t] = x;
    }
}

// ---------------- tiled f32 GEMM -> bf16 interleaved hev ----------------
template <int K, int OFFH>
__global__ __launch_bounds__(256) void gemm_f32(const float* __restrict__ A, const float* __restrict__ B,
                                                unsigned* __restrict__ hevu, int M) {
    constexpr int BM = 64, BK = 32;
    __shared__ float Ast[BK][BM];     // transposed A tile
    __shared__ float Bs[BK][128];
    int t = threadIdx.x;
    int bm = blockIdx.x * BM;
    int tx = t & 15, ty = t >> 4;     // tx: 8-col group, ty: 4-row group
    float acc[4][8] = {};
    for (int k0 = 0; k0 < K; k0 += BK) {
        for (int c = t; c < BM * BK / 4; c += 256) {
            int row = c >> 3, pos = (c & 7) << 2;
            float4 v = make_float4(0.f, 0.f, 0.f, 0.f);
            int gr = bm + row;
            if (gr < M) v = *reinterpret_cast<const float4*>(A + (size_t)gr * K + k0 + pos);
            Ast[pos + 0][row] = v.x; Ast[pos + 1][row] = v.y;
            Ast[pos + 2][row] = v.z; Ast[pos + 3][row] = v.w;
        }
        for (int c = t; c < BK * 128 / 4; c += 256) {
            int row = c >> 5, pos = (c & 31) << 2;
            *reinterpret_cast<float4*>(&Bs[row][pos]) =
                *reinterpret_cast<const float4*>(B + (size_t)(k0 + row) * 128 + pos);
        }
        __syncthreads();
#pragma unroll
        for (int kk = 0; kk < BK; ++kk) {
            float4 a = *reinterpret_cast<const float4*>(&Ast[kk][ty * 4]);
            float4 b0 = *reinterpret_cast<const float4*>(&Bs[kk][tx * 8]);
            float4 b1 = *reinterpret_cast<const float4*>(&Bs[kk][tx * 8 + 4]);
            const float* av = reinterpret_cast<const float*>(&a);
            const float* bv0 = reinterpret_cast<const float*>(&b0);
            const float* bv1 = reinterpret_cast<const float*>(&b1);
#pragma unroll
            for (int r = 0; r < 4; ++r) {
#pragma unroll
                for (int c = 0; c < 4; ++c) {
                    acc[r][c] += av[r] * bv0[c];
                    acc[r][c + 4] += av[r] * bv1[c];
                }
            }
        }
        __syncthreads();
    }
#pragma unroll
    for (int r = 0; r < 4; ++r) {
        int gr = bm + ty * 4 + r;
        if (gr < M) {
            unsigned* rowp = hevu + (size_t)gr * 128;
#pragma unroll
            for (int p = 0; p < 4; ++p) {
                rowp[((tx * 4 + p) << 1) + OFFH] = bf16pair(acc[r][2 * p], acc[r][2 * p + 1]);
            }
        }
    }
}

// ---------------- per-node scalars s1,s2,t1 (wave per row, K=256) ----------------
__global__ void node_scalars(const float* __restrict__ NF, const float* __restrict__ w1,
                             const float* __restrict__ w2, const float* __restrict__ w3,
                             float* __restrict__ s1, float* __restrict__ s2, float* __restrict__ t1) {
    int wave = (int)((blockIdx.x * (size_t)blockDim.x + threadIdx.x) >> 6);
    int lane = threadIdx.x & 63;
    if (wave >= NN) return;
    const float* row = NF + (size_t)wave * 256;
    float4 v = *reinterpret_cast<const float4*>(row + lane * 4);
    float a = 0.f, b = 0.f, c = 0.f;
    const float* x = reinterpret_cast<const float*>(&v);
#pragma unroll
    for (int j = 0; j < 4; ++j) {
        a += x[j] * w1[lane * 4 + j];
        b += x[j] * w2[lane * 4 + j];
        c += x[j] * w3[lane * 4 + j];
    }
    for (int off = 32; off; off >>= 1) {
        a += __shfl_down(a, off);
        b += __shfl_down(b, off);
        c += __shfl_down(c, off);
    }
    if (lane == 0) { s1[wave] = a; s2[wave] = b; t1[wave] = c; }
}

// ---------------- per-edge scalar t2e (wave per row, K=128) ----------------
__global__ void edge_scalar(const float* __restrict__ EF, const float* __restrict__ w,
                            float* __restrict__ t2e) {
    int wave = (int)((blockIdx.x * (size_t)blockDim.x + threadIdx.x) >> 6);
    int lane = threadIdx.x & 63;
    if (wave >= EE) return;
    float2 v = *reinterpret_cast<const float2*>(EF + (size_t)wave * 128 + lane * 2);
    float a = v.x * w[lane * 2] + v.y * w[lane * 2 + 1];
    for (int off = 32; off; off >>= 1) a += __shfl_down(a, off);
    if (lane == 0) t2e[wave] = a;
}

// ---------------- per-edge attention: ONE packed u64 atomic per edge-end ----------------
// histR[rep*NN+s] packed: count(8) | qnatt(28) | qeatt(28), fixed-point 2^17.
// atomic return's count field == this edge's rank within its (rep,s) bucket.
__global__ void attention(const int* __restrict__ edges, const float* __restrict__ s1,
                          const float* __restrict__ s2, const float* __restrict__ t1,
                          const float* __restrict__ t2e, float* __restrict__ natt,
                          float* __restrict__ eatt, unsigned long long* __restrict__ histR,
                          unsigned* __restrict__ rank) {
    int i = blockIdx.x * blockDim.x + threadIdx.x;
    if (i >= 2 * EE) return;
    int rep = blockIdx.x & (REPS - 1);
    int s, d, j;
    if (i < EE) { j = i; int2 p = *reinterpret_cast<const int2*>(edges + 2 * j); s = p.x; d = p.y; }
    else        { j = i - EE; int2 p = *reinterpret_cast<const int2*>(edges + 2 * j); s = p.y; d = p.x; }
    float xn = s1[s] + s2[d];
    xn = xn >= 0.f ? xn : 0.2f * xn;
    xn = fminf(fmaxf(xn, -2.f), 2.f);
    float na = expf(xn);
    float xe = t1[s] + t2e[j];
    xe = xe >= 0.f ? xe : 0.2f * xe;
    xe = fminf(fmaxf(xe, -2.f), 2.f);
    float ea = expf(xe);
    natt[i] = na; eatt[i] = ea;
    unsigned qn = __float2uint_rn(na * QSCALE);
    unsigned qe = __float2uint_rn(ea * QSCALE);
    unsigned long long pk = (1ULL << 56) | ((unsigned long long)qn << 28) | (unsigned long long)qe;
    unsigned long long old = atomicAdd(&histR[(size_t)rep * NN + s], pk);
    rank[i] = (unsigned)(old >> 56);
}

// ---------------- fold replicas (packed u64 sums are carry-safe) ----------------
__global__ void reduce_reps(const unsigned long long* __restrict__ histR, float* __restrict__ nsum,
                            float* __restrict__ esum, int* __restrict__ counts) {
    int n = blockIdx.x * blockDim.x + threadIdx.x;
    if (n >= NN) return;
    unsigned long long h = 0;
    for (int g = 0; g < REPS; ++g) h += histR[(size_t)g * NN + n];
    counts[n] = (int)(h >> 56);
    nsum[n] = (float)((h >> 28) & 0x0FFFFFFFULL) * (1.0f / QSCALE);
    esum[n] = (float)(h & 0x0FFFFFFFULL) * (1.0f / QSCALE);
}

// ---------------- scan: counts -> offsets (exclusive) ----------------
#define SCAN_CHUNK 2048
__global__ void scan_block_sums(const int* __restrict__ counts, int* __restrict__ bsums) {
    __shared__ int sdata[256];
    int b = blockIdx.x, t = threadIdx.x;
    int base = b * SCAN_CHUNK + t * 8;
    int s = 0;
    for (int j = 0; j < 8; ++j) { int idx = base + j; if (idx < NN) s += counts[idx]; }
    sdata[t] = s; __syncthreads();
    for (int off = 128; off; off >>= 1) { if (t < off) sdata[t] += sdata[t + off]; __syncthreads(); }
    if (t == 0) bsums[b] = sdata[0];
}
__global__ void scan_bsums(int* __restrict__ bsums, int nb) {
    if (threadIdx.x == 0 && blockIdx.x == 0) {
        int run = 0;
        for (int i = 0; i < nb; ++i) { int v = bsums[i]; bsums[i] = run; run += v; }
    }
}
__global__ void scan_final(const int* __restrict__ counts, const int* __restrict__ bsums,
                           int* __restrict__ offsets) {
    __shared__ int sdata[256];
    int b = blockIdx.x, t = threadIdx.x;
    int base = b * SCAN_CHUNK + t * 8;
    int loc[8]; int s = 0;
    for (int j = 0; j < 8; ++j) { int idx = base + j; int v = (idx < NN) ? counts[idx] : 0; loc[j] = v; s += v; }
    sdata[t] = s; __syncthreads();
    for (int off = 1; off < 256; off <<= 1) {
        int v = (t >= off) ? sdata[t - off] : 0;
        __syncthreads();
        sdata[t] += v;
        __syncthreads();
    }
    int run = sdata[t] - s + bsums[b];
    for (int j = 0; j < 8; ++j) {
        int idx = base + j;
        if (idx < NN) { offsets[idx] = run; run += loc[j]; }
    }
}

// ---------------- per-replica cursors from packed replica counts (no atomics later) ----------------
__global__ void make_cursorR(const unsigned long long* __restrict__ histR,
                             const int* __restrict__ offsets, int* __restrict__ cursorR) {
    int n = blockIdx.x * blockDim.x + threadIdx.x;
    if (n >= NN) return;
    int run = offsets[n];
    for (int g = 0; g < REPS; ++g) {
        cursorR[(size_t)g * NN + n] = run;
        run += (int)(histR[(size_t)g * NN + n] >> 56);
    }
}

// ---------------- fill position->node map g ----------------
__global__ void fill_g(const int* __restrict__ offsets, const int* __restrict__ counts,
                       int* __restrict__ g) {
    int n = blockIdx.x * blockDim.x + threadIdx.x;
    if (n >= NN) return;
    int o = offsets[n], c = counts[n];
    for (int k = 0; k < c; ++k) g[o + k] = n;
}

// ---------------- normalize + atomic-free CSR meta scatter + variance ----------------
__global__ void normalize_var(const float* __restrict__ natt, const float* __restrict__ eatt,
                              const float* __restrict__ nsum, const float* __restrict__ esum,
                              const int* __restrict__ g, const int* __restrict__ edges,
                              const int* __restrict__ cursorR, const unsigned* __restrict__ rank,
                              float4* __restrict__ meta, double* __restrict__ acc) {
    int i = blockIdx.x * blockDim.x + threadIdx.x;
    float nn = 0.f, en = 0.f;
    if (i < 2 * EE) {
        int gi = g[i];
        nn = natt[i] / nsum[gi];
        en = eatt[i] / esum[gi];
        int s, d;
        if (i < EE) { int2 p = *reinterpret_cast<const int2*>(edges + 2 * i); s = p.x; d = p.y; }
        else        { int2 p = *reinterpret_cast<const int2*>(edges + 2 * (i - EE)); s = p.y; d = p.x; }
        int rep = (i >> 8) & (REPS - 1);   // must match attention's block->rep mapping
        int slot = cursorR[(size_t)rep * NN + s] + (int)rank[i];
        meta[slot] = make_float4(__int_as_float(d), nn, en, 0.f);
    }
    double v[4] = { (double)nn, (double)nn * nn, (double)en, (double)en * en };
    __shared__ double sd[4][4];
    int lane = threadIdx.x & 63, wv = threadIdx.x >> 6;
#pragma unroll
    for (int q = 0; q < 4; ++q) {
        double x = v[q];
        for (int off = 32; off; off >>= 1) x += __shfl_down(x, off);
        if (lane == 0) sd[q][wv] = x;
    }
    __syncthreads();
    if (threadIdx.x < 4) {
        double x = sd[threadIdx.x][0] + sd[threadIdx.x][1] + sd[threadIdx.x][2] + sd[threadIdx.x][3];
        atomicAdd(&acc[threadIdx.x], x);
    }
}

// ---------------- CSR accumulate: wave per node, 2-deep pipelined bf16 gathers ----------------
__global__ void accumulate(const float4* __restrict__ meta, const int* __restrict__ offsets,
                           const int* __restrict__ counts, const uint2* __restrict__ hev,
                           float* __restrict__ node_out, float* __restrict__ edge_out) {
    int wave = (int)((blockIdx.x * (size_t)blockDim.x + threadIdx.x) >> 6);
    int lane = threadIdx.x & 63;
    if (wave >= NN) return;
    int o = offsets[wave], c = counts[wave];
    float aH0 = 0.f, aH1 = 0.f, aE0 = 0.f, aE1 = 0.f;
    float4 z = make_float4(0.f, 0.f, 0.f, 0.f);
    float4 m0 = (c > 0) ? meta[o] : z;
    float4 m1 = (c > 1) ? meta[o + 1] : m0;
    float4 m2 = (c > 2) ? meta[o + 2] : m1;
    uint2 v0 = make_uint2(0u, 0u);
    if (c > 0) v0 = hev[(size_t)__float_as_int(m0.x) * 64 + lane];
    for (int k = 0; k < c; ++k) {
        uint2 v1 = v0;
        if (k + 1 < c) v1 = hev[(size_t)__float_as_int(m1.x) * 64 + lane];
        float4 m3 = (k + 3 < c) ? meta[o + k + 3] : m2;
        float h0 = __uint_as_float(v0.x << 16);
        float h1 = __uint_as_float(v0.x & 0xFFFF0000u);
        float e0 = __uint_as_float(v0.y << 16);
        float e1 = __uint_as_float(v0.y & 0xFFFF0000u);
        aH0 += h0 * m0.y; aH1 += h1 * m0.y;
        aE0 += e0 * m0.z; aE1 += e1 * m0.z;
        m0 = m1; m1 = m2; m2 = m3; v0 = v1;
    }
    float2 rn = { aH0, aH1 }, re = { aE0, aE1 };
    *reinterpret_cast<float2*>(node_out + (size_t)wave * 128 + lane * 2) = rn;
    *reinterpret_cast<float2*>(edge_out + (size_t)wave * 128 + lane * 2) = re;
}

// ---------------- finalize variance ----------------
__global__ void finalize_var(const double* __restrict__ acc, float* __restrict__ out_var) {
    if (threadIdx.x == 0 && blockIdx.x == 0) {
        double M = 2.0 * EE;
        double nv = (acc[1] - acc[0] * acc[0] / M) / (M - 1.0);
        double ev = (acc[3] - acc[2] * acc[2] / M) / (M - 1.0);
        out_var[0] = (float)nv;
        out_var[1] = (float)ev;
    }
}

extern "C" void kernel_launch(void* const* d_in, const int* in_sizes, int n_in,
                              void* d_out, int out_size, void* d_ws, size_t ws_size,
                              hipStream_t stream) {
    const float* node_fts = (const float*)d_in[0];
    const float* edge_fts = (const float*)d_in[1];
    const int*   edges    = (const int*)d_in[2];
    const float* W_node   = (const float*)d_in[3];
    const float* W_edge   = (const float*)d_in[4];
    const float* a_node   = (const float*)d_in[5];
    const float* a_edge   = (const float*)d_in[6];
    float* out = (float*)d_out;

    char* w = (char*)d_ws;
    auto alloc = [&](size_t bytes) -> void* {
        void* p = (void*)w;
        w += (bytes + 255) & ~(size_t)255;
        return p;
    };
    unsigned* hevu = (unsigned*)alloc((size_t)NN * 512);        // bf16 interleaved h/e rows
    float* s1    = (float*)alloc(NN * 4);
    float* s2    = (float*)alloc(NN * 4);
    float* t1    = (float*)alloc(NN * 4);
    float* t2e   = (float*)alloc(EE * 4);
    float* natt  = (float*)alloc(2 * EE * 4);
    float* eatt  = (float*)alloc(2 * EE * 4);
    unsigned* rank = (unsigned*)alloc((size_t)2 * EE * 4);
    float4* meta = (float4*)alloc((size_t)2 * EE * 16);
    int*   offsets = (int*)alloc((NN + 1) * 4);
    int*   g       = (int*)alloc(2 * EE * 4);
    int*   bsums   = (int*)alloc(64 * 4);
    float* wn_a1 = (float*)alloc(256 * 4);
    float* wn_a2 = (float*)alloc(256 * 4);
    float* wn_e1 = (float*)alloc(256 * 4);
    float* we_a2 = (float*)alloc(128 * 4);
    float* nsum   = (float*)alloc(NN * 4);
    float* esum   = (float*)alloc(NN * 4);
    int*   counts = (int*)alloc(NN * 4);
    int*   cursorR = (int*)alloc((size_t)REPS * NN * 4);
    // contiguous zero block: histR (u64), acc (4 doubles)
    char* zb = (char*)alloc((size_t)REPS * NN * 8 + 64);
    unsigned long long* histR = (unsigned long long*)zb;
    double* acc = (double*)(zb + (size_t)REPS * NN * 8);

    hipMemsetAsync(zb, 0, (size_t)REPS * NN * 8 + 64, stream);

    prep_vectors<<<1, 256, 0, stream>>>(W_node, W_edge, a_node, a_edge, wn_a1, wn_a2, wn_e1, we_a2);

    const int gemm_grid = (NN + 63) / 64;  // 782
    gemm_f32<256, 0><<<gemm_grid, 256, 0, stream>>>(node_fts, W_node, hevu, NN);
    gemm_f32<128, 1><<<gemm_grid, 256, 0, stream>>>(edge_fts, W_edge, hevu, NN);

    node_scalars<<<(NN + 3) / 4, 256, 0, stream>>>(node_fts, wn_a1, wn_a2, wn_e1, s1, s2, t1);
    edge_scalar<<<(EE + 3) / 4, 256, 0, stream>>>(edge_fts, we_a2, t2e);

    attention<<<(2 * EE + 255) / 256, 256, 0, stream>>>(edges, s1, s2, t1, t2e, natt, eatt,
                                                        histR, rank);

    reduce_reps<<<(NN + 255) / 256, 256, 0, stream>>>(histR, nsum, esum, counts);

    const int nscan = (NN + SCAN_CHUNK - 1) / SCAN_CHUNK;  // 25
    scan_block_sums<<<nscan, 256, 0, stream>>>(counts, bsums);
    scan_bsums<<<1, 64, 0, stream>>>(bsums, nscan);
    scan_final<<<nscan, 256, 0, stream>>>(counts, bsums, offsets);

    make_cursorR<<<(NN + 255) / 256, 256, 0, stream>>>(histR, offsets, cursorR);
    fill_g<<<(NN + 255) / 256, 256, 0, stream>>>(offsets, counts, g);

    normalize_var<<<(2 * EE + 255) / 256, 256, 0, stream>>>(natt, eatt, nsum, esum, g, edges,
                                                            cursorR, rank, meta, acc);

    accumulate<<<(NN + 3) / 4, 256, 0, stream>>>(meta, offsets, counts, (const uint2*)hevu,
                                                 out, out + (size_t)NN * 128);

    finalize_var<<<1, 64, 0, stream>>>(acc, out + (size_t)2 * NN * 128);
}

// Round 5
// 381.012 us; speedup vs baseline: 1.2333x; 1.0650x over previous
//
#include <hip/hip_runtime.h>
#include <hip/hip_bf16.h>

#define NN 50000
#define EE 400000
#define REPS 16
#define QSCALE 131072.0f   // 2^17 fixed-point scale for packed histogram
#define SCAN_CHUNK 2048

typedef short bf16x8 __attribute__((ext_vector_type(8)));
typedef float f32x4 __attribute__((ext_vector_type(4)));

__device__ inline unsigned bf16pair(float a, float b) {
    unsigned ua = __float_as_uint(a), ub = __float_as_uint(b);
    ua = (ua + 0x7FFFu + ((ua >> 16) & 1u)) >> 16;
    ub = (ub + 0x7FFFu + ((ub >> 16) & 1u)) >> 16;
    return ua | (ub << 16);
}

// ---------------- prep: fold a-vectors through W (block 0) + transpose W to bf16 (all) ----------------
__global__ void prep(const float* __restrict__ W_node, const float* __restrict__ W_edge,
                     const float* __restrict__ a_node, const float* __restrict__ a_edge,
                     float* wn_a1, float* wn_a2, float* wn_e1, float* we_a2,
                     unsigned short* __restrict__ Wt_node, unsigned short* __restrict__ Wt_edge) {
    int t = threadIdx.x;
    if (blockIdx.x == 0) {
        if (t < 256) {
            float x1 = 0.f, x2 = 0.f, x3 = 0.f;
            for (int j = 0; j < 128; ++j) {
                float w = W_node[t * 128 + j];
                x1 += w * a_node[j];
                x2 += w * a_node[128 + j];
                x3 += w * a_edge[j];
            }
            wn_a1[t] = x1; wn_a2[t] = x2; wn_e1[t] = x3;
        }
        if (t < 128) {
            float x = 0.f;
            for (int j = 0; j < 128; ++j) x += W_edge[t * 128 + j] * a_edge[128 + j];
            we_a2[t] = x;
        }
    }
    int gid = blockIdx.x * blockDim.x + t;
    int nth = gridDim.x * blockDim.x;
    for (int idx = gid; idx < 256 * 128; idx += nth) {
        int r = idx >> 7, c = idx & 127;
        unsigned u = __float_as_uint(W_node[idx]);
        u = (u + 0x7FFFu + ((u >> 16) & 1u)) >> 16;
        Wt_node[c * 256 + r] = (unsigned short)u;
    }
    for (int idx = gid; idx < 128 * 128; idx += nth) {
        int r = idx >> 7, c = idx & 127;
        unsigned u = __float_as_uint(W_edge[idx]);
        u = (u + 0x7FFFu + ((u >> 16) & 1u)) >> 16;
        Wt_edge[c * 128 + r] = (unsigned short)u;
    }
}

// ---------------- MFMA bf16 GEMM, LDS-free, fused per-row scalar dots ----------------
// C[M][128] = A[M][K] @ W[K][128]; Wt is W transposed bf16 [128][K].
// Output packed bf16 pairs into hevu rows (uint idx = col + OFFH for even col).
// FUSE3: also compute s1,s2,t1 = A @ w1,w2,w3 (o1,o2,o3); else only o3 = A @ w3.
template <int K, int OFFH, bool FUSE3>
__global__ __launch_bounds__(256) void gemm_mfma(const float* __restrict__ A,
                                                 const unsigned short* __restrict__ Wt,
                                                 const float* __restrict__ w1,
                                                 const float* __restrict__ w2,
                                                 const float* __restrict__ w3,
                                                 unsigned* __restrict__ hevu,
                                                 float* __restrict__ o1, float* __restrict__ o2,
                                                 float* __restrict__ o3, int M) {
    int t = threadIdx.x;
    int wv = t >> 6, l = t & 63;
    int rl = l & 15, kg = l >> 4;          // lane row (and B col), k-group
    int wrow0 = blockIdx.x * 64 + wv * 16;
    int gr = wrow0 + rl;
    int ar = gr < M ? gr : M - 1;
    const float* Arow = A + (size_t)ar * K;
    f32x4 acc[8];
#pragma unroll
    for (int i = 0; i < 8; ++i) acc[i] = (f32x4){0.f, 0.f, 0.f, 0.f};
    float p1 = 0.f, p2 = 0.f, p3 = 0.f;
    for (int k0 = 0; k0 < K; k0 += 32) {
        int kb = k0 + kg * 8;
        float4 alo = *reinterpret_cast<const float4*>(Arow + kb);
        float4 ahi = *reinterpret_cast<const float4*>(Arow + kb + 4);
        union { unsigned u[4]; bf16x8 v; } af;
        af.u[0] = bf16pair(alo.x, alo.y);
        af.u[1] = bf16pair(alo.z, alo.w);
        af.u[2] = bf16pair(ahi.x, ahi.y);
        af.u[3] = bf16pair(ahi.z, ahi.w);
        if (FUSE3) {
            float4 wl = *reinterpret_cast<const float4*>(w1 + kb);
            float4 wh = *reinterpret_cast<const float4*>(w1 + kb + 4);
            p1 += alo.x * wl.x + alo.y * wl.y + alo.z * wl.z + alo.w * wl.w
                + ahi.x * wh.x + ahi.y * wh.y + ahi.z * wh.z + ahi.w * wh.w;
            wl = *reinterpret_cast<const float4*>(w2 + kb);
            wh = *reinterpret_cast<const float4*>(w2 + kb + 4);
            p2 += alo.x * wl.x + alo.y * wl.y + alo.z * wl.z + alo.w * wl.w
                + ahi.x * wh.x + ahi.y * wh.y + ahi.z * wh.z + ahi.w * wh.w;
        }
        {
            float4 wl = *reinterpret_cast<const float4*>(w3 + kb);
            float4 wh = *reinterpret_cast<const float4*>(w3 + kb + 4);
            p3 += alo.x * wl.x + alo.y * wl.y + alo.z * wl.z + alo.w * wl.w
                + ahi.x * wh.x + ahi.y * wh.y + ahi.z * wh.z + ahi.w * wh.w;
        }
#pragma unroll
        for (int nt = 0; nt < 8; ++nt) {
            union { unsigned u[4]; bf16x8 v; } bf;
            const unsigned* bp = reinterpret_cast<const unsigned*>(Wt + (size_t)(rl + 16 * nt) * K + kb);
            bf.u[0] = bp[0]; bf.u[1] = bp[1]; bf.u[2] = bp[2]; bf.u[3] = bp[3];
            acc[nt] = __builtin_amdgcn_mfma_f32_16x16x32_bf16(af.v, bf.v, acc[nt], 0, 0, 0);
        }
    }
    // fused scalar outputs: reduce partial dots across the 4 k-groups
    p3 += __shfl_xor(p3, 16); p3 += __shfl_xor(p3, 32);
    if (FUSE3) {
        p1 += __shfl_xor(p1, 16); p1 += __shfl_xor(p1, 32);
        p2 += __shfl_xor(p2, 16); p2 += __shfl_xor(p2, 32);
        if (l < 16 && gr < M) { o1[gr] = p1; o2[gr] = p2; o3[gr] = p3; }
    } else {
        if (l < 16 && gr < M) o3[gr] = p3;
    }
    // epilogue: D[row=(kg*4+reg)][col=rl+16nt] -> bf16 pairs; even lanes write regs 0,1; odd regs 2,3
#pragma unroll
    for (int nt = 0; nt < 8; ++nt) {
#pragma unroll
        for (int reg = 0; reg < 4; ++reg) {
            float mine = acc[nt][reg];
            float other = __shfl_xor(mine, 1);
            int orow = wrow0 + kg * 4 + reg;
            if (orow < M) {
                int col = rl + 16 * nt;
                if (!(l & 1)) {
                    if (reg < 2) hevu[(size_t)orow * 128 + col + OFFH] = bf16pair(mine, other);
                } else {
                    if (reg >= 2) hevu[(size_t)orow * 128 + (col - 1) + OFFH] = bf16pair(other, mine);
                }
            }
        }
    }
}

// ---------------- per-edge scalar t2e for rows [NN, EE) (wave per row, K=128) ----------------
__global__ void edge_scalar_tail(const float* __restrict__ EF, const float* __restrict__ w,
                                 float* __restrict__ t2e) {
    int wave = NN + (int)((blockIdx.x * (size_t)blockDim.x + threadIdx.x) >> 6);
    int lane = threadIdx.x & 63;
    if (wave >= EE) return;
    float2 v = *reinterpret_cast<const float2*>(EF + (size_t)wave * 128 + lane * 2);
    float a = v.x * w[lane * 2] + v.y * w[lane * 2 + 1];
    for (int off = 32; off; off >>= 1) a += __shfl_down(a, off);
    if (lane == 0) t2e[wave] = a;
}

// ---------------- per-edge attention: ONE packed u64 atomic per edge-end ----------------
__global__ void attention(const int* __restrict__ edges, const float* __restrict__ s1,
                          const float* __restrict__ s2, const float* __restrict__ t1,
                          const float* __restrict__ t2e, float* __restrict__ natt,
                          float* __restrict__ eatt, unsigned long long* __restrict__ histR,
                          unsigned* __restrict__ rank) {
    int i = blockIdx.x * blockDim.x + threadIdx.x;
    if (i >= 2 * EE) return;
    int rep = blockIdx.x & (REPS - 1);
    int s, d, j;
    if (i < EE) { j = i; int2 p = *reinterpret_cast<const int2*>(edges + 2 * j); s = p.x; d = p.y; }
    else        { j = i - EE; int2 p = *reinterpret_cast<const int2*>(edges + 2 * j); s = p.y; d = p.x; }
    float xn = s1[s] + s2[d];
    xn = xn >= 0.f ? xn : 0.2f * xn;
    xn = fminf(fmaxf(xn, -2.f), 2.f);
    float na = expf(xn);
    float xe = t1[s] + t2e[j];
    xe = xe >= 0.f ? xe : 0.2f * xe;
    xe = fminf(fmaxf(xe, -2.f), 2.f);
    float ea = expf(xe);
    natt[i] = na; eatt[i] = ea;
    unsigned qn = __float2uint_rn(na * QSCALE);
    unsigned qe = __float2uint_rn(ea * QSCALE);
    unsigned long long pk = (1ULL << 56) | ((unsigned long long)qn << 28) | (unsigned long long)qe;
    unsigned long long old = atomicAdd(&histR[(size_t)rep * NN + s], pk);
    rank[i] = (unsigned)(old >> 56);
}

// ---------------- fold replicas + per-scan-chunk count sums (absorbs scan_block_sums) ----------------
__global__ void reduce_reps(const unsigned long long* __restrict__ histR, float* __restrict__ nsum,
                            float* __restrict__ esum, int* __restrict__ counts,
                            int* __restrict__ bsums) {
    __shared__ int sdata[256];
    int b = blockIdx.x, t = threadIdx.x;
    int base = b * SCAN_CHUNK;
    int csum = 0;
    for (int j = 0; j < 8; ++j) {
        int idx = base + j * 256 + t;
        if (idx < NN) {
            unsigned long long h = 0;
            for (int g = 0; g < REPS; ++g) h += histR[(size_t)g * NN + idx];
            int c = (int)(h >> 56);
            counts[idx] = c;
            nsum[idx] = (float)((h >> 28) & 0x0FFFFFFFULL) * (1.0f / QSCALE);
            esum[idx] = (float)(h & 0x0FFFFFFFULL) * (1.0f / QSCALE);
            csum += c;
        }
    }
    sdata[t] = csum; __syncthreads();
    for (int off = 128; off; off >>= 1) { if (t < off) sdata[t] += sdata[t + off]; __syncthreads(); }
    if (t == 0) bsums[b] = sdata[0];
}

__global__ void scan_bsums(int* __restrict__ bsums, int nb) {
    if (threadIdx.x == 0 && blockIdx.x == 0) {
        int run = 0;
        for (int i = 0; i < nb; ++i) { int v = bsums[i]; bsums[i] = run; run += v; }
    }
}

// ---------------- final scan: offsets + per-replica cursors + position->node map g ----------------
__global__ void scan_final(const int* __restrict__ counts, const int* __restrict__ bsums,
                           const unsigned long long* __restrict__ histR,
                           int* __restrict__ offsets, int* __restrict__ cursorR,
                           int* __restrict__ g) {
    __shared__ int sdata[256];
    int b = blockIdx.x, t = threadIdx.x;
    int base = b * SCAN_CHUNK + t * 8;
    int loc[8]; int s = 0;
    for (int j = 0; j < 8; ++j) { int idx = base + j; int v = (idx < NN) ? counts[idx] : 0; loc[j] = v; s += v; }
    sdata[t] = s; __syncthreads();
    for (int off = 1; off < 256; off <<= 1) {
        int v = (t >= off) ? sdata[t - off] : 0;
        __syncthreads();
        sdata[t] += v;
        __syncthreads();
    }
    int run = sdata[t] - s + bsums[b];
    for (int j = 0; j < 8; ++j) {
        int idx = base + j;
        if (idx < NN) {
            offsets[idx] = run;
            int r2 = run;
            for (int gg = 0; gg < REPS; ++gg) {
                cursorR[(size_t)gg * NN + idx] = r2;
                r2 += (int)(histR[(size_t)gg * NN + idx] >> 56);
            }
            for (int k = 0; k < loc[j]; ++k) g[run + k] = idx;
            run += loc[j];
        }
    }
}

// ---------------- normalize + atomic-free CSR meta scatter + variance ----------------
__global__ void normalize_var(const float* __restrict__ natt, const float* __restrict__ eatt,
                              const float* __restrict__ nsum, const float* __restrict__ esum,
                              const int* __restrict__ g, const int* __restrict__ edges,
                              const int* __restrict__ cursorR, const unsigned* __restrict__ rank,
                              float4* __restrict__ meta, double* __restrict__ acc) {
    int i = blockIdx.x * blockDim.x + threadIdx.x;
    float nn = 0.f, en = 0.f;
    if (i < 2 * EE) {
        int gi = g[i];
        nn = natt[i] / nsum[gi];
        en = eatt[i] / esum[gi];
        int s, d;
        if (i < EE) { int2 p = *reinterpret_cast<const int2*>(edges + 2 * i); s = p.x; d = p.y; }
        else        { int2 p = *reinterpret_cast<const int2*>(edges + 2 * (i - EE)); s = p.y; d = p.x; }
        int rep = (i >> 8) & (REPS - 1);   // must match attention's block->rep mapping
        int slot = cursorR[(size_t)rep * NN + s] + (int)rank[i];
        meta[slot] = make_float4(__int_as_float(d), nn, en, 0.f);
    }
    double v[4] = { (double)nn, (double)nn * nn, (double)en, (double)en * en };
    __shared__ double sd[4][4];
    int lane = threadIdx.x & 63, wv = threadIdx.x >> 6;
#pragma unroll
    for (int q = 0; q < 4; ++q) {
        double x = v[q];
        for (int off = 32; off; off >>= 1) x += __shfl_down(x, off);
        if (lane == 0) sd[q][wv] = x;
    }
    __syncthreads();
    if (threadIdx.x < 4) {
        double x = sd[threadIdx.x][0] + sd[threadIdx.x][1] + sd[threadIdx.x][2] + sd[threadIdx.x][3];
        atomicAdd(&acc[threadIdx.x], x);
    }
}

// ---------------- CSR accumulate: wave per node, 2-deep pipelined bf16 gathers ----------------
__global__ void accumulate(const float4* __restrict__ meta, const int* __restrict__ offsets,
                           const int* __restrict__ counts, const uint2* __restrict__ hev,
                           float* __restrict__ node_out, float* __restrict__ edge_out) {
    int wave = (int)((blockIdx.x * (size_t)blockDim.x + threadIdx.x) >> 6);
    int lane = threadIdx.x & 63;
    if (wave >= NN) return;
    int o = offsets[wave], c = counts[wave];
    float aH0 = 0.f, aH1 = 0.f, aE0 = 0.f, aE1 = 0.f;
    float4 z = make_float4(0.f, 0.f, 0.f, 0.f);
    float4 m0 = (c > 0) ? meta[o] : z;
    float4 m1 = (c > 1) ? meta[o + 1] : m0;
    float4 m2 = (c > 2) ? meta[o + 2] : m1;
    uint2 v0 = make_uint2(0u, 0u);
    if (c > 0) v0 = hev[(size_t)__float_as_int(m0.x) * 64 + lane];
    for (int k = 0; k < c; ++k) {
        uint2 v1 = v0;
        if (k + 1 < c) v1 = hev[(size_t)__float_as_int(m1.x) * 64 + lane];
        float4 m3 = (k + 3 < c) ? meta[o + k + 3] : m2;
        float h0 = __uint_as_float(v0.x << 16);
        float h1 = __uint_as_float(v0.x & 0xFFFF0000u);
        float e0 = __uint_as_float(v0.y << 16);
        float e1 = __uint_as_float(v0.y & 0xFFFF0000u);
        aH0 += h0 * m0.y; aH1 += h1 * m0.y;
        aE0 += e0 * m0.z; aE1 += e1 * m0.z;
        m0 = m1; m1 = m2; m2 = m3; v0 = v1;
    }
    float2 rn = { aH0, aH1 }, re = { aE0, aE1 };
    *reinterpret_cast<float2*>(node_out + (size_t)wave * 128 + lane * 2) = rn;
    *reinterpret_cast<float2*>(edge_out + (size_t)wave * 128 + lane * 2) = re;
}

// ---------------- finalize variance ----------------
__global__ void finalize_var(const double* __restrict__ acc, float* __restrict__ out_var) {
    if (threadIdx.x == 0 && blockIdx.x == 0) {
        double M = 2.0 * EE;
        double nv = (acc[1] - acc[0] * acc[0] / M) / (M - 1.0);
        double ev = (acc[3] - acc[2] * acc[2] / M) / (M - 1.0);
        out_var[0] = (float)nv;
        out_var[1] = (float)ev;
    }
}

extern "C" void kernel_launch(void* const* d_in, const int* in_sizes, int n_in,
                              void* d_out, int out_size, void* d_ws, size_t ws_size,
                              hipStream_t stream) {
    const float* node_fts = (const float*)d_in[0];
    const float* edge_fts = (const float*)d_in[1];
    const int*   edges    = (const int*)d_in[2];
    const float* W_node   = (const float*)d_in[3];
    const float* W_edge   = (const float*)d_in[4];
    const float* a_node   = (const float*)d_in[5];
    const float* a_edge   = (const float*)d_in[6];
    float* out = (float*)d_out;

    char* w = (char*)d_ws;
    auto alloc = [&](size_t bytes) -> void* {
        void* p = (void*)w;
        w += (bytes + 255) & ~(size_t)255;
        return p;
    };
    unsigned* hevu = (unsigned*)alloc((size_t)NN * 512);        // bf16 interleaved h/e rows
    float* s1    = (float*)alloc(NN * 4);
    float* s2    = (float*)alloc(NN * 4);
    float* t1    = (float*)alloc(NN * 4);
    float* t2e   = (float*)alloc(EE * 4);
    float* natt  = (float*)alloc(2 * EE * 4);
    float* eatt  = (float*)alloc(2 * EE * 4);
    unsigned* rank = (unsigned*)alloc((size_t)2 * EE * 4);
    float4* meta = (float4*)alloc((size_t)2 * EE * 16);
    int*   offsets = (int*)alloc((NN + 1) * 4);
    int*   g       = (int*)alloc(2 * EE * 4);
    int*   bsums   = (int*)alloc(64 * 4);
    float* wn_a1 = (float*)alloc(256 * 4);
    float* wn_a2 = (float*)alloc(256 * 4);
    float* wn_e1 = (float*)alloc(256 * 4);
    float* we_a2 = (float*)alloc(128 * 4);
    unsigned short* Wt_node = (unsigned short*)alloc(256 * 128 * 2);
    unsigned short* Wt_edge = (unsigned short*)alloc(128 * 128 * 2);
    float* nsum   = (float*)alloc(NN * 4);
    float* esum   = (float*)alloc(NN * 4);
    int*   counts = (int*)alloc(NN * 4);
    int*   cursorR = (int*)alloc((size_t)REPS * NN * 4);
    // contiguous zero block: histR (u64), acc (4 doubles)
    char* zb = (char*)alloc((size_t)REPS * NN * 8 + 64);
    unsigned long long* histR = (unsigned long long*)zb;
    double* acc = (double*)(zb + (size_t)REPS * NN * 8);

    hipMemsetAsync(zb, 0, (size_t)REPS * NN * 8 + 64, stream);

    prep<<<64, 256, 0, stream>>>(W_node, W_edge, a_node, a_edge, wn_a1, wn_a2, wn_e1, we_a2,
                                 Wt_node, Wt_edge);

    const int gemm_grid = (NN + 63) / 64;  // 782
    gemm_mfma<256, 0, true><<<gemm_grid, 256, 0, stream>>>(node_fts, Wt_node, wn_a1, wn_a2, wn_e1,
                                                           hevu, s1, s2, t1, NN);
    gemm_mfma<128, 1, false><<<gemm_grid, 256, 0, stream>>>(edge_fts, Wt_edge, nullptr, nullptr,
                                                            we_a2, hevu, nullptr, nullptr, t2e, NN);

    edge_scalar_tail<<<((EE - NN) + 3) / 4, 256, 0, stream>>>(edge_fts, we_a2, t2e);

    attention<<<(2 * EE + 255) / 256, 256, 0, stream>>>(edges, s1, s2, t1, t2e, natt, eatt,
                                                        histR, rank);

    const int nscan = (NN + SCAN_CHUNK - 1) / SCAN_CHUNK;  // 25
    reduce_reps<<<nscan, 256, 0, stream>>>(histR, nsum, esum, counts, bsums);
    scan_bsums<<<1, 64, 0, stream>>>(bsums, nscan);
    scan_final<<<nscan, 256, 0, stream>>>(counts, bsums, histR, offsets, cursorR, g);

    normalize_var<<<(2 * EE + 255) / 256, 256, 0, stream>>>(natt, eatt, nsum, esum, g, edges,
                                                            cursorR, rank, meta, acc);

    accumulate<<<(NN + 3) / 4, 256, 0, stream>>>(meta, offsets, counts, (const uint2*)hevu,
                                                 out, out + (size_t)NN * 128);

    finalize_var<<<1, 64, 0, stream>>>(acc, out + (size_t)2 * NN * 128);
}

// Round 6
// 377.885 us; speedup vs baseline: 1.2435x; 1.0083x over previous
//
#include <hip/hip_runtime.h>
#include <hip/hip_bf16.h>

#define NN 50000
#define EE 400000
#define REPS 16
#define QSCALE 131072.0f   // 2^17 fixed-point scale for packed histogram
#define SCAN_CHUNK 2048

typedef short bf16x8 __attribute__((ext_vector_type(8)));
typedef float f32x4 __attribute__((ext_vector_type(4)));

__device__ inline unsigned bf16pair(float a, float b) {
    unsigned ua = __float_as_uint(a), ub = __float_as_uint(b);
    ua = (ua + 0x7FFFu + ((ua >> 16) & 1u)) >> 16;
    ub = (ub + 0x7FFFu + ((ub >> 16) & 1u)) >> 16;
    return ua | (ub << 16);
}

// ---------------- fast workspace zero (replaces pathologically slow rocclr fill) ----------------
__global__ void zero_ws(unsigned long long* __restrict__ p, size_t n64) {
    size_t i = (size_t)blockIdx.x * blockDim.x + threadIdx.x;
    size_t stride = (size_t)gridDim.x * blockDim.x;
    for (; i < n64; i += stride) p[i] = 0ULL;
}

// ---------------- prep: fold a-vectors through W (block 0) + transpose W to bf16 (all) ----------------
__global__ void prep(const float* __restrict__ W_node, const float* __restrict__ W_edge,
                     const float* __restrict__ a_node, const float* __restrict__ a_edge,
                     float* wn_a1, float* wn_a2, float* wn_e1, float* we_a2,
                     unsigned short* __restrict__ Wt_node, unsigned short* __restrict__ Wt_edge) {
    int t = threadIdx.x;
    if (blockIdx.x == 0) {
        if (t < 256) {
            float x1 = 0.f, x2 = 0.f, x3 = 0.f;
            for (int j = 0; j < 128; ++j) {
                float w = W_node[t * 128 + j];
                x1 += w * a_node[j];
                x2 += w * a_node[128 + j];
                x3 += w * a_edge[j];
            }
            wn_a1[t] = x1; wn_a2[t] = x2; wn_e1[t] = x3;
        }
        if (t < 128) {
            float x = 0.f;
            for (int j = 0; j < 128; ++j) x += W_edge[t * 128 + j] * a_edge[128 + j];
            we_a2[t] = x;
        }
    }
    int gid = blockIdx.x * blockDim.x + t;
    int nth = gridDim.x * blockDim.x;
    for (int idx = gid; idx < 256 * 128; idx += nth) {
        int r = idx >> 7, c = idx & 127;
        unsigned u = __float_as_uint(W_node[idx]);
        u = (u + 0x7FFFu + ((u >> 16) & 1u)) >> 16;
        Wt_node[c * 256 + r] = (unsigned short)u;
    }
    for (int idx = gid; idx < 128 * 128; idx += nth) {
        int r = idx >> 7, c = idx & 127;
        unsigned u = __float_as_uint(W_edge[idx]);
        u = (u + 0x7FFFu + ((u >> 16) & 1u)) >> 16;
        Wt_edge[c * 128 + r] = (unsigned short)u;
    }
}

// ---------------- MFMA bf16 GEMM, LDS-free, fused per-row scalar dots ----------------
template <int K, int OFFH, bool FUSE3>
__global__ __launch_bounds__(256) void gemm_mfma(const float* __restrict__ A,
                                                 const unsigned short* __restrict__ Wt,
                                                 const float* __restrict__ w1,
                                                 const float* __restrict__ w2,
                                                 const float* __restrict__ w3,
                                                 unsigned* __restrict__ hevu,
                                                 float* __restrict__ o1, float* __restrict__ o2,
                                                 float* __restrict__ o3, int M) {
    int t = threadIdx.x;
    int wv = t >> 6, l = t & 63;
    int rl = l & 15, kg = l >> 4;          // lane row (and B col), k-group
    int wrow0 = blockIdx.x * 64 + wv * 16;
    int gr = wrow0 + rl;
    int ar = gr < M ? gr : M - 1;
    const float* Arow = A + (size_t)ar * K;
    f32x4 acc[8];
#pragma unroll
    for (int i = 0; i < 8; ++i) acc[i] = (f32x4){0.f, 0.f, 0.f, 0.f};
    float p1 = 0.f, p2 = 0.f, p3 = 0.f;
    for (int k0 = 0; k0 < K; k0 += 32) {
        int kb = k0 + kg * 8;
        float4 alo = *reinterpret_cast<const float4*>(Arow + kb);
        float4 ahi = *reinterpret_cast<const float4*>(Arow + kb + 4);
        union { unsigned u[4]; bf16x8 v; } af;
        af.u[0] = bf16pair(alo.x, alo.y);
        af.u[1] = bf16pair(alo.z, alo.w);
        af.u[2] = bf16pair(ahi.x, ahi.y);
        af.u[3] = bf16pair(ahi.z, ahi.w);
        if (FUSE3) {
            float4 wl = *reinterpret_cast<const float4*>(w1 + kb);
            float4 wh = *reinterpret_cast<const float4*>(w1 + kb + 4);
            p1 += alo.x * wl.x + alo.y * wl.y + alo.z * wl.z + alo.w * wl.w
                + ahi.x * wh.x + ahi.y * wh.y + ahi.z * wh.z + ahi.w * wh.w;
            wl = *reinterpret_cast<const float4*>(w2 + kb);
            wh = *reinterpret_cast<const float4*>(w2 + kb + 4);
            p2 += alo.x * wl.x + alo.y * wl.y + alo.z * wl.z + alo.w * wl.w
                + ahi.x * wh.x + ahi.y * wh.y + ahi.z * wh.z + ahi.w * wh.w;
        }
        {
            float4 wl = *reinterpret_cast<const float4*>(w3 + kb);
            float4 wh = *reinterpret_cast<const float4*>(w3 + kb + 4);
            p3 += alo.x * wl.x + alo.y * wl.y + alo.z * wl.z + alo.w * wl.w
                + ahi.x * wh.x + ahi.y * wh.y + ahi.z * wh.z + ahi.w * wh.w;
        }
#pragma unroll
        for (int nt = 0; nt < 8; ++nt) {
            union { unsigned u[4]; bf16x8 v; } bf;
            const unsigned* bp = reinterpret_cast<const unsigned*>(Wt + (size_t)(rl + 16 * nt) * K + kb);
            bf.u[0] = bp[0]; bf.u[1] = bp[1]; bf.u[2] = bp[2]; bf.u[3] = bp[3];
            acc[nt] = __builtin_amdgcn_mfma_f32_16x16x32_bf16(af.v, bf.v, acc[nt], 0, 0, 0);
        }
    }
    // fused scalar outputs: reduce partial dots across the 4 k-groups
    p3 += __shfl_xor(p3, 16); p3 += __shfl_xor(p3, 32);
    if (FUSE3) {
        p1 += __shfl_xor(p1, 16); p1 += __shfl_xor(p1, 32);
        p2 += __shfl_xor(p2, 16); p2 += __shfl_xor(p2, 32);
        if (l < 16 && gr < M) { o1[gr] = p1; o2[gr] = p2; o3[gr] = p3; }
    } else {
        if (l < 16 && gr < M) o3[gr] = p3;
    }
    // epilogue: D[row=(kg*4+reg)][col=rl+16nt] -> bf16 pairs
#pragma unroll
    for (int nt = 0; nt < 8; ++nt) {
#pragma unroll
        for (int reg = 0; reg < 4; ++reg) {
            float mine = acc[nt][reg];
            float other = __shfl_xor(mine, 1);
            int orow = wrow0 + kg * 4 + reg;
            if (orow < M) {
                int col = rl + 16 * nt;
                if (!(l & 1)) {
                    if (reg < 2) hevu[(size_t)orow * 128 + col + OFFH] = bf16pair(mine, other);
                } else {
                    if (reg >= 2) hevu[(size_t)orow * 128 + (col - 1) + OFFH] = bf16pair(other, mine);
                }
            }
        }
    }
}

// ---------------- per-edge scalar t2e for rows [NN, EE) (wave per row, K=128) ----------------
__global__ void edge_scalar_tail(const float* __restrict__ EF, const float* __restrict__ w,
                                 float* __restrict__ t2e) {
    int wave = NN + (int)((blockIdx.x * (size_t)blockDim.x + threadIdx.x) >> 6);
    int lane = threadIdx.x & 63;
    if (wave >= EE) return;
    float2 v = *reinterpret_cast<const float2*>(EF + (size_t)wave * 128 + lane * 2);
    float a = v.x * w[lane * 2] + v.y * w[lane * 2 + 1];
    for (int off = 32; off; off >>= 1) a += __shfl_down(a, off);
    if (lane == 0) t2e[wave] = a;
}

// ---------------- per-edge attention: ONE packed u64 atomic per edge-end ----------------
__global__ void attention(const int* __restrict__ edges, const float* __restrict__ s1,
                          const float* __restrict__ s2, const float* __restrict__ t1,
                          const float* __restrict__ t2e, float* __restrict__ natt,
                          float* __restrict__ eatt, unsigned long long* __restrict__ histR,
                          unsigned* __restrict__ rank) {
    int i = blockIdx.x * blockDim.x + threadIdx.x;
    if (i >= 2 * EE) return;
    int rep = blockIdx.x & (REPS - 1);
    int s, d, j;
    if (i < EE) { j = i; int2 p = *reinterpret_cast<const int2*>(edges + 2 * j); s = p.x; d = p.y; }
    else        { j = i - EE; int2 p = *reinterpret_cast<const int2*>(edges + 2 * j); s = p.y; d = p.x; }
    float xn = s1[s] + s2[d];
    xn = xn >= 0.f ? xn : 0.2f * xn;
    xn = fminf(fmaxf(xn, -2.f), 2.f);
    float na = expf(xn);
    float xe = t1[s] + t2e[j];
    xe = xe >= 0.f ? xe : 0.2f * xe;
    xe = fminf(fmaxf(xe, -2.f), 2.f);
    float ea = expf(xe);
    natt[i] = na; eatt[i] = ea;
    unsigned qn = __float2uint_rn(na * QSCALE);
    unsigned qe = __float2uint_rn(ea * QSCALE);
    unsigned long long pk = (1ULL << 56) | ((unsigned long long)qn << 28) | (unsigned long long)qe;
    unsigned long long old = atomicAdd(&histR[(size_t)rep * NN + s], pk);
    rank[i] = (unsigned)(old >> 56);
}

// ---------------- fold replicas + per-scan-chunk count sums ----------------
__global__ void reduce_reps(const unsigned long long* __restrict__ histR, float* __restrict__ nsum,
                            float* __restrict__ esum, int* __restrict__ counts,
                            int* __restrict__ bsums) {
    __shared__ int sdata[256];
    int b = blockIdx.x, t = threadIdx.x;
    int base = b * SCAN_CHUNK;
    int csum = 0;
    for (int j = 0; j < 8; ++j) {
        int idx = base + j * 256 + t;
        if (idx < NN) {
            unsigned long long h = 0;
            for (int g = 0; g < REPS; ++g) h += histR[(size_t)g * NN + idx];
            int c = (int)(h >> 56);
            counts[idx] = c;
            nsum[idx] = (float)((h >> 28) & 0x0FFFFFFFULL) * (1.0f / QSCALE);
            esum[idx] = (float)(h & 0x0FFFFFFFULL) * (1.0f / QSCALE);
            csum += c;
        }
    }
    sdata[t] = csum; __syncthreads();
    for (int off = 128; off; off >>= 1) { if (t < off) sdata[t] += sdata[t + off]; __syncthreads(); }
    if (t == 0) bsums[b] = sdata[0];
}

__global__ void scan_bsums(int* __restrict__ bsums, int nb) {
    if (threadIdx.x == 0 && blockIdx.x == 0) {
        int run = 0;
        for (int i = 0; i < nb; ++i) { int v = bsums[i]; bsums[i] = run; run += v; }
    }
}

// ---------------- final scan: offsets + per-replica cursors + position->node map g ----------------
__global__ void scan_final(const int* __restrict__ counts, const int* __restrict__ bsums,
                           const unsigned long long* __restrict__ histR,
                           int* __restrict__ offsets, int* __restrict__ cursorR,
                           int* __restrict__ g) {
    __shared__ int sdata[256];
    int b = blockIdx.x, t = threadIdx.x;
    int base = b * SCAN_CHUNK + t * 8;
    int loc[8]; int s = 0;
    for (int j = 0; j < 8; ++j) { int idx = base + j; int v = (idx < NN) ? counts[idx] : 0; loc[j] = v; s += v; }
    sdata[t] = s; __syncthreads();
    for (int off = 1; off < 256; off <<= 1) {
        int v = (t >= off) ? sdata[t - off] : 0;
        __syncthreads();
        sdata[t] += v;
        __syncthreads();
    }
    int run = sdata[t] - s + bsums[b];
    for (int j = 0; j < 8; ++j) {
        int idx = base + j;
        if (idx < NN) {
            offsets[idx] = run;
            int r2 = run;
            for (int gg = 0; gg < REPS; ++gg) {
                cursorR[(size_t)gg * NN + idx] = r2;
                r2 += (int)(histR[(size_t)gg * NN + idx] >> 56);
            }
            for (int k = 0; k < loc[j]; ++k) g[run + k] = idx;
            run += loc[j];
        }
    }
}

// ---------------- normalize + atomic-free CSR meta scatter + variance ----------------
__global__ void normalize_var(const float* __restrict__ natt, const float* __restrict__ eatt,
                              const float* __restrict__ nsum, const float* __restrict__ esum,
                              const int* __restrict__ g, const int* __restrict__ edges,
                              const int* __restrict__ cursorR, const unsigned* __restrict__ rank,
                              float4* __restrict__ meta, double* __restrict__ acc) {
    int i = blockIdx.x * blockDim.x + threadIdx.x;
    float nn = 0.f, en = 0.f;
    if (i < 2 * EE) {
        int gi = g[i];
        nn = natt[i] / nsum[gi];
        en = eatt[i] / esum[gi];
        int s, d;
        if (i < EE) { int2 p = *reinterpret_cast<const int2*>(edges + 2 * i); s = p.x; d = p.y; }
        else        { int2 p = *reinterpret_cast<const int2*>(edges + 2 * (i - EE)); s = p.y; d = p.x; }
        int rep = (i >> 8) & (REPS - 1);   // must match attention's block->rep mapping
        int slot = cursorR[(size_t)rep * NN + s] + (int)rank[i];
        meta[slot] = make_float4(__int_as_float(d), nn, en, 0.f);
    }
    double v[4] = { (double)nn, (double)nn * nn, (double)en, (double)en * en };
    __shared__ double sd[4][4];
    int lane = threadIdx.x & 63, wv = threadIdx.x >> 6;
#pragma unroll
    for (int q = 0; q < 4; ++q) {
        double x = v[q];
        for (int off = 32; off; off >>= 1) x += __shfl_down(x, off);
        if (lane == 0) sd[q][wv] = x;
    }
    __syncthreads();
    if (threadIdx.x < 4) {
        double x = sd[threadIdx.x][0] + sd[threadIdx.x][1] + sd[threadIdx.x][2] + sd[threadIdx.x][3];
        atomicAdd(&acc[threadIdx.x], x);
    }
}

// ---------------- CSR accumulate: wave per node, 2-deep pipelined bf16 gathers ----------------
__global__ void accumulate(const float4* __restrict__ meta, const int* __restrict__ offsets,
                           const int* __restrict__ counts, const uint2* __restrict__ hev,
                           float* __restrict__ node_out, float* __restrict__ edge_out) {
    int wave = (int)((blockIdx.x * (size_t)blockDim.x + threadIdx.x) >> 6);
    int lane = threadIdx.x & 63;
    if (wave >= NN) return;
    int o = offsets[wave], c = counts[wave];
    float aH0 = 0.f, aH1 = 0.f, aE0 = 0.f, aE1 = 0.f;
    float4 z = make_float4(0.f, 0.f, 0.f, 0.f);
    float4 m0 = (c > 0) ? meta[o] : z;
    float4 m1 = (c > 1) ? meta[o + 1] : m0;
    float4 m2 = (c > 2) ? meta[o + 2] : m1;
    uint2 v0 = make_uint2(0u, 0u);
    if (c > 0) v0 = hev[(size_t)__float_as_int(m0.x) * 64 + lane];
    for (int k = 0; k < c; ++k) {
        uint2 v1 = v0;
        if (k + 1 < c) v1 = hev[(size_t)__float_as_int(m1.x) * 64 + lane];
        float4 m3 = (k + 3 < c) ? meta[o + k + 3] : m2;
        float h0 = __uint_as_float(v0.x << 16);
        float h1 = __uint_as_float(v0.x & 0xFFFF0000u);
        float e0 = __uint_as_float(v0.y << 16);
        float e1 = __uint_as_float(v0.y & 0xFFFF0000u);
        aH0 += h0 * m0.y; aH1 += h1 * m0.y;
        aE0 += e0 * m0.z; aE1 += e1 * m0.z;
        m0 = m1; m1 = m2; m2 = m3; v0 = v1;
    }
    float2 rn = { aH0, aH1 }, re = { aE0, aE1 };
    *reinterpret_cast<float2*>(node_out + (size_t)wave * 128 + lane * 2) = rn;
    *reinterpret_cast<float2*>(edge_out + (size_t)wave * 128 + lane * 2) = re;
}

// ---------------- finalize variance ----------------
__global__ void finalize_var(const double* __restrict__ acc, float* __restrict__ out_var) {
    if (threadIdx.x == 0 && blockIdx.x == 0) {
        double M = 2.0 * EE;
        double nv = (acc[1] - acc[0] * acc[0] / M) / (M - 1.0);
        double ev = (acc[3] - acc[2] * acc[2] / M) / (M - 1.0);
        out_var[0] = (float)nv;
        out_var[1] = (float)ev;
    }
}

extern "C" void kernel_launch(void* const* d_in, const int* in_sizes, int n_in,
                              void* d_out, int out_size, void* d_ws, size_t ws_size,
                              hipStream_t stream) {
    const float* node_fts = (const float*)d_in[0];
    const float* edge_fts = (const float*)d_in[1];
    const int*   edges    = (const int*)d_in[2];
    const float* W_node   = (const float*)d_in[3];
    const float* W_edge   = (const float*)d_in[4];
    const float* a_node   = (const float*)d_in[5];
    const float* a_edge   = (const float*)d_in[6];
    float* out = (float*)d_out;

    char* w = (char*)d_ws;
    auto alloc = [&](size_t bytes) -> void* {
        void* p = (void*)w;
        w += (bytes + 255) & ~(size_t)255;
        return p;
    };
    unsigned* hevu = (unsigned*)alloc((size_t)NN * 512);        // bf16 interleaved h/e rows
    float* s1    = (float*)alloc(NN * 4);
    float* s2    = (float*)alloc(NN * 4);
    float* t1    = (float*)alloc(NN * 4);
    float* t2e   = (float*)alloc(EE * 4);
    float* natt  = (float*)alloc(2 * EE * 4);
    float* eatt  = (float*)alloc(2 * EE * 4);
    unsigned* rank = (unsigned*)alloc((size_t)2 * EE * 4);
    float4* meta = (float4*)alloc((size_t)2 * EE * 16);
    int*   offsets = (int*)alloc((NN + 1) * 4);
    int*   g       = (int*)alloc(2 * EE * 4);
    int*   bsums   = (int*)alloc(64 * 4);
    float* wn_a1 = (float*)alloc(256 * 4);
    float* wn_a2 = (float*)alloc(256 * 4);
    float* wn_e1 = (float*)alloc(256 * 4);
    float* we_a2 = (float*)alloc(128 * 4);
    unsigned short* Wt_node = (unsigned short*)alloc(256 * 128 * 2);
    unsigned short* Wt_edge = (unsigned short*)alloc(128 * 128 * 2);
    float* nsum   = (float*)alloc(NN * 4);
    float* esum   = (float*)alloc(NN * 4);
    int*   counts = (int*)alloc(NN * 4);
    int*   cursorR = (int*)alloc((size_t)REPS * NN * 4);
    // contiguous zero block: histR (u64), acc (4 doubles)
    char* zb = (char*)alloc((size_t)REPS * NN * 8 + 64);
    unsigned long long* histR = (unsigned long long*)zb;
    double* acc = (double*)(zb + (size_t)REPS * NN * 8);

    const size_t n64 = (size_t)REPS * NN + 8;
    zero_ws<<<(int)((n64 + 255) / 256), 256, 0, stream>>>((unsigned long long*)zb, n64);

    prep<<<64, 256, 0, stream>>>(W_node, W_edge, a_node, a_edge, wn_a1, wn_a2, wn_e1, we_a2,
                                 Wt_node, Wt_edge);

    const int gemm_grid = (NN + 63) / 64;  // 782
    gemm_mfma<256, 0, true><<<gemm_grid, 256, 0, stream>>>(node_fts, Wt_node, wn_a1, wn_a2, wn_e1,
                                                           hevu, s1, s2, t1, NN);
    gemm_mfma<128, 1, false><<<gemm_grid, 256, 0, stream>>>(edge_fts, Wt_edge, nullptr, nullptr,
                                                            we_a2, hevu, nullptr, nullptr, t2e, NN);

    edge_scalar_tail<<<((EE - NN) + 3) / 4, 256, 0, stream>>>(edge_fts, we_a2, t2e);

    attention<<<(2 * EE + 255) / 256, 256, 0, stream>>>(edges, s1, s2, t1, t2e, natt, eatt,
                                                        histR, rank);

    const int nscan = (NN + SCAN_CHUNK - 1) / SCAN_CHUNK;  // 25
    reduce_reps<<<nscan, 256, 0, stream>>>(histR, nsum, esum, counts, bsums);
    scan_bsums<<<1, 64, 0, stream>>>(bsums, nscan);
    scan_final<<<nscan, 256, 0, stream>>>(counts, bsums, histR, offsets, cursorR, g);

    normalize_var<<<(2 * EE + 255) / 256, 256, 0, stream>>>(natt, eatt, nsum, esum, g, edges,
                                                            cursorR, rank, meta, acc);

    accumulate<<<(NN + 3) / 4, 256, 0, stream>>>(meta, offsets, counts, (const uint2*)hevu,
                                                 out, out + (size_t)NN * 128);

    finalize_var<<<1, 64, 0, stream>>>(acc, out + (size_t)2 * NN * 128);
}

// Round 7
// 360.040 us; speedup vs baseline: 1.3052x; 1.0496x over previous
//
#include <hip/hip_runtime.h>
#include <hip/hip_bf16.h>

#define NN 50000
#define EE 400000
#define REPS 16
#define QSCALE 131072.0f   // 2^17 fixed-point scale for packed histogram
#define SCAN_CHUNK 2048

typedef short bf16x8 __attribute__((ext_vector_type(8)));
typedef float f32x4 __attribute__((ext_vector_type(4)));

__device__ inline unsigned bf16pair(float a, float b) {
    unsigned ua = __float_as_uint(a), ub = __float_as_uint(b);
    ua = (ua + 0x7FFFu + ((ua >> 16) & 1u)) >> 16;
    ub = (ub + 0x7FFFu + ((ub >> 16) & 1u)) >> 16;
    return ua | (ub << 16);
}

// ---------------- fast workspace zero ----------------
__global__ void zero_ws(unsigned long long* __restrict__ p, size_t n64) {
    size_t i = (size_t)blockIdx.x * blockDim.x + threadIdx.x;
    size_t stride = (size_t)gridDim.x * blockDim.x;
    for (; i < n64; i += stride) p[i] = 0ULL;
}

// ---------------- prep: fold a-vectors through W (block 0) + transpose W to bf16 (all) ----------------
__global__ void prep(const float* __restrict__ W_node, const float* __restrict__ W_edge,
                     const float* __restrict__ a_node, const float* __restrict__ a_edge,
                     float* wn_a1, float* wn_a2, float* wn_e1, float* we_a2,
                     unsigned short* __restrict__ Wt_node, unsigned short* __restrict__ Wt_edge) {
    int t = threadIdx.x;
    if (blockIdx.x == 0) {
        if (t < 256) {
            float x1 = 0.f, x2 = 0.f, x3 = 0.f;
            for (int j = 0; j < 128; ++j) {
                float w = W_node[t * 128 + j];
                x1 += w * a_node[j];
                x2 += w * a_node[128 + j];
                x3 += w * a_edge[j];
            }
            wn_a1[t] = x1; wn_a2[t] = x2; wn_e1[t] = x3;
        }
        if (t < 128) {
            float x = 0.f;
            for (int j = 0; j < 128; ++j) x += W_edge[t * 128 + j] * a_edge[128 + j];
            we_a2[t] = x;
        }
    }
    int gid = blockIdx.x * blockDim.x + t;
    int nth = gridDim.x * blockDim.x;
    for (int idx = gid; idx < 256 * 128; idx += nth) {
        int r = idx >> 7, c = idx & 127;
        unsigned u = __float_as_uint(W_node[idx]);
        u = (u + 0x7FFFu + ((u >> 16) & 1u)) >> 16;
        Wt_node[c * 256 + r] = (unsigned short)u;
    }
    for (int idx = gid; idx < 128 * 128; idx += nth) {
        int r = idx >> 7, c = idx & 127;
        unsigned u = __float_as_uint(W_edge[idx]);
        u = (u + 0x7FFFu + ((u >> 16) & 1u)) >> 16;
        Wt_edge[c * 128 + r] = (unsigned short)u;
    }
}

// ---------------- MFMA bf16 GEMM, LDS-free, fused per-row scalar dots ----------------
template <int K, int OFFH, bool FUSE3>
__global__ __launch_bounds__(256) void gemm_mfma(const float* __restrict__ A,
                                                 const unsigned short* __restrict__ Wt,
                                                 const float* __restrict__ w1,
                                                 const float* __restrict__ w2,
                                                 const float* __restrict__ w3,
                                                 unsigned* __restrict__ hevu,
                                                 float* __restrict__ o1, float* __restrict__ o2,
                                                 float* __restrict__ o3, int M) {
    int t = threadIdx.x;
    int wv = t >> 6, l = t & 63;
    int rl = l & 15, kg = l >> 4;          // lane row (and B col), k-group
    int wrow0 = blockIdx.x * 64 + wv * 16;
    int gr = wrow0 + rl;
    int ar = gr < M ? gr : M - 1;
    const float* Arow = A + (size_t)ar * K;
    f32x4 acc[8];
#pragma unroll
    for (int i = 0; i < 8; ++i) acc[i] = (f32x4){0.f, 0.f, 0.f, 0.f};
    float p1 = 0.f, p2 = 0.f, p3 = 0.f;
    for (int k0 = 0; k0 < K; k0 += 32) {
        int kb = k0 + kg * 8;
        float4 alo = *reinterpret_cast<const float4*>(Arow + kb);
        float4 ahi = *reinterpret_cast<const float4*>(Arow + kb + 4);
        union { unsigned u[4]; bf16x8 v; } af;
        af.u[0] = bf16pair(alo.x, alo.y);
        af.u[1] = bf16pair(alo.z, alo.w);
        af.u[2] = bf16pair(ahi.x, ahi.y);
        af.u[3] = bf16pair(ahi.z, ahi.w);
        if (FUSE3) {
            float4 wl = *reinterpret_cast<const float4*>(w1 + kb);
            float4 wh = *reinterpret_cast<const float4*>(w1 + kb + 4);
            p1 += alo.x * wl.x + alo.y * wl.y + alo.z * wl.z + alo.w * wl.w
                + ahi.x * wh.x + ahi.y * wh.y + ahi.z * wh.z + ahi.w * wh.w;
            wl = *reinterpret_cast<const float4*>(w2 + kb);
            wh = *reinterpret_cast<const float4*>(w2 + kb + 4);
            p2 += alo.x * wl.x + alo.y * wl.y + alo.z * wl.z + alo.w * wl.w
                + ahi.x * wh.x + ahi.y * wh.y + ahi.z * wh.z + ahi.w * wh.w;
        }
        {
            float4 wl = *reinterpret_cast<const float4*>(w3 + kb);
            float4 wh = *reinterpret_cast<const float4*>(w3 + kb + 4);
            p3 += alo.x * wl.x + alo.y * wl.y + alo.z * wl.z + alo.w * wl.w
                + ahi.x * wh.x + ahi.y * wh.y + ahi.z * wh.z + ahi.w * wh.w;
        }
#pragma unroll
        for (int nt = 0; nt < 8; ++nt) {
            union { unsigned u[4]; bf16x8 v; } bf;
            const unsigned* bp = reinterpret_cast<const unsigned*>(Wt + (size_t)(rl + 16 * nt) * K + kb);
            bf.u[0] = bp[0]; bf.u[1] = bp[1]; bf.u[2] = bp[2]; bf.u[3] = bp[3];
            acc[nt] = __builtin_amdgcn_mfma_f32_16x16x32_bf16(af.v, bf.v, acc[nt], 0, 0, 0);
        }
    }
    p3 += __shfl_xor(p3, 16); p3 += __shfl_xor(p3, 32);
    if (FUSE3) {
        p1 += __shfl_xor(p1, 16); p1 += __shfl_xor(p1, 32);
        p2 += __shfl_xor(p2, 16); p2 += __shfl_xor(p2, 32);
        if (l < 16 && gr < M) { o1[gr] = p1; o2[gr] = p2; o3[gr] = p3; }
    } else {
        if (l < 16 && gr < M) o3[gr] = p3;
    }
#pragma unroll
    for (int nt = 0; nt < 8; ++nt) {
#pragma unroll
        for (int reg = 0; reg < 4; ++reg) {
            float mine = acc[nt][reg];
            float other = __shfl_xor(mine, 1);
            int orow = wrow0 + kg * 4 + reg;
            if (orow < M) {
                int col = rl + 16 * nt;
                if (!(l & 1)) {
                    if (reg < 2) hevu[(size_t)orow * 128 + col + OFFH] = bf16pair(mine, other);
                } else {
                    if (reg >= 2) hevu[(size_t)orow * 128 + (col - 1) + OFFH] = bf16pair(other, mine);
                }
            }
        }
    }
}

// ---------------- per-edge scalar t2e for rows [NN, EE) ----------------
__global__ void edge_scalar_tail(const float* __restrict__ EF, const float* __restrict__ w,
                                 float* __restrict__ t2e) {
    int wave = NN + (int)((blockIdx.x * (size_t)blockDim.x + threadIdx.x) >> 6);
    int lane = threadIdx.x & 63;
    if (wave >= EE) return;
    float2 v = *reinterpret_cast<const float2*>(EF + (size_t)wave * 128 + lane * 2);
    float a = v.x * w[lane * 2] + v.y * w[lane * 2 + 1];
    for (int off = 32; off; off >>= 1) a += __shfl_down(a, off);
    if (lane == 0) t2e[wave] = a;
}

// ---------------- per-edge attention: ONE packed u64 atomic per edge-end, rank only ----------------
__global__ void attention(const int* __restrict__ edges, const float* __restrict__ s1,
                          const float* __restrict__ s2, const float* __restrict__ t1,
                          const float* __restrict__ t2e, unsigned long long* __restrict__ histR,
                          unsigned* __restrict__ rank) {
    int i = blockIdx.x * blockDim.x + threadIdx.x;
    if (i >= 2 * EE) return;
    int rep = blockIdx.x & (REPS - 1);
    int s, d, j;
    if (i < EE) { j = i; int2 p = *reinterpret_cast<const int2*>(edges + 2 * j); s = p.x; d = p.y; }
    else        { j = i - EE; int2 p = *reinterpret_cast<const int2*>(edges + 2 * j); s = p.y; d = p.x; }
    float xn = s1[s] + s2[d];
    xn = xn >= 0.f ? xn : 0.2f * xn;
    xn = fminf(fmaxf(xn, -2.f), 2.f);
    float na = expf(xn);
    float xe = t1[s] + t2e[j];
    xe = xe >= 0.f ? xe : 0.2f * xe;
    xe = fminf(fmaxf(xe, -2.f), 2.f);
    float ea = expf(xe);
    unsigned qn = __float2uint_rn(na * QSCALE);
    unsigned qe = __float2uint_rn(ea * QSCALE);
    unsigned long long pk = (1ULL << 56) | ((unsigned long long)qn << 28) | (unsigned long long)qe;
    unsigned long long old = atomicAdd(&histR[(size_t)rep * NN + s], pk);
    rank[i] = (unsigned)(old >> 56);
}

// ---------------- fold replicas + per-scan-chunk count sums ----------------
__global__ void reduce_reps(const unsigned long long* __restrict__ histR, float* __restrict__ nsum,
                            float* __restrict__ esum, int* __restrict__ counts,
                            int* __restrict__ bsums) {
    __shared__ int sdata[256];
    int b = blockIdx.x, t = threadIdx.x;
    int base = b * SCAN_CHUNK;
    int csum = 0;
    for (int j = 0; j < 8; ++j) {
        int idx = base + j * 256 + t;
        if (idx < NN) {
            unsigned long long h = 0;
            for (int g = 0; g < REPS; ++g) h += histR[(size_t)g * NN + idx];
            int c = (int)(h >> 56);
            counts[idx] = c;
            nsum[idx] = (float)((h >> 28) & 0x0FFFFFFFULL) * (1.0f / QSCALE);
            esum[idx] = (float)(h & 0x0FFFFFFFULL) * (1.0f / QSCALE);
            csum += c;
        }
    }
    sdata[t] = csum; __syncthreads();
    for (int off = 128; off; off >>= 1) { if (t < off) sdata[t] += sdata[t + off]; __syncthreads(); }
    if (t == 0) bsums[b] = sdata[0];
}

__global__ void scan_bsums(int* __restrict__ bsums, int nb) {
    if (threadIdx.x == 0 && blockIdx.x == 0) {
        int run = 0;
        for (int i = 0; i < nb; ++i) { int v = bsums[i]; bsums[i] = run; run += v; }
    }
}

// ---------------- final scan: offsets + per-replica cursors + position->node map g ----------------
__global__ void scan_final(const int* __restrict__ counts, const int* __restrict__ bsums,
                           const unsigned long long* __restrict__ histR,
                           int* __restrict__ offsets, int* __restrict__ cursorR,
                           int* __restrict__ g) {
    __shared__ int sdata[256];
    int b = blockIdx.x, t = threadIdx.x;
    int base = b * SCAN_CHUNK + t * 8;
    int loc[8]; int s = 0;
    for (int j = 0; j < 8; ++j) { int idx = base + j; int v = (idx < NN) ? counts[idx] : 0; loc[j] = v; s += v; }
    sdata[t] = s; __syncthreads();
    for (int off = 1; off < 256; off <<= 1) {
        int v = (t >= off) ? sdata[t - off] : 0;
        __syncthreads();
        sdata[t] += v;
        __syncthreads();
    }
    int run = sdata[t] - s + bsums[b];
    for (int j = 0; j < 8; ++j) {
        int idx = base + j;
        if (idx < NN) {
            offsets[idx] = run;
            int r2 = run;
            for (int gg = 0; gg < REPS; ++gg) {
                cursorR[(size_t)gg * NN + idx] = r2;
                r2 += (int)(histR[(size_t)gg * NN + idx] >> 56);
            }
            for (int k = 0; k < loc[j]; ++k) g[run + k] = idx;
            run += loc[j];
        }
    }
}

// ---------------- normalize (recompute exp) + atomic-free CSR meta scatter + variance ----------------
__global__ void normalize_var(const float* __restrict__ s1, const float* __restrict__ s2,
                              const float* __restrict__ t1, const float* __restrict__ t2e,
                              const float* __restrict__ nsum, const float* __restrict__ esum,
                              const int* __restrict__ g, const int* __restrict__ edges,
                              const int* __restrict__ cursorR, const unsigned* __restrict__ rank,
                              float4* __restrict__ meta, double* __restrict__ acc) {
    int i = blockIdx.x * blockDim.x + threadIdx.x;
    float nn = 0.f, en = 0.f;
    if (i < 2 * EE) {
        int s, d, j;
        if (i < EE) { j = i; int2 p = *reinterpret_cast<const int2*>(edges + 2 * j); s = p.x; d = p.y; }
        else        { j = i - EE; int2 p = *reinterpret_cast<const int2*>(edges + 2 * j); s = p.y; d = p.x; }
        float xn = s1[s] + s2[d];
        xn = xn >= 0.f ? xn : 0.2f * xn;
        xn = fminf(fmaxf(xn, -2.f), 2.f);
        float na = expf(xn);
        float xe = t1[s] + t2e[j];
        xe = xe >= 0.f ? xe : 0.2f * xe;
        xe = fminf(fmaxf(xe, -2.f), 2.f);
        float ea = expf(xe);
        int gi = g[i];
        nn = na / nsum[gi];
        en = ea / esum[gi];
        int rep = (i >> 8) & (REPS - 1);   // must match attention's block->rep mapping
        int slot = cursorR[(size_t)rep * NN + s] + (int)rank[i];
        meta[slot] = make_float4(__int_as_float(d), nn, en, 0.f);
    }
    double v[4] = { (double)nn, (double)nn * nn, (double)en, (double)en * en };
    __shared__ double sd[4][4];
    int lane = threadIdx.x & 63, wv = threadIdx.x >> 6;
#pragma unroll
    for (int q = 0; q < 4; ++q) {
        double x = v[q];
        for (int off = 32; off; off >>= 1) x += __shfl_down(x, off);
        if (lane == 0) sd[q][wv] = x;
    }
    __syncthreads();
    if (threadIdx.x < 4) {
        double x = sd[threadIdx.x][0] + sd[threadIdx.x][1] + sd[threadIdx.x][2] + sd[threadIdx.x][3];
        atomicAdd(&acc[threadIdx.x], x);
    }
}

// ---------------- CSR accumulate: wave per node, TWO edges per trip (half-wave uint4 gathers) ----------------
__global__ void accumulate(const float4* __restrict__ meta, const int* __restrict__ offsets,
                           const int* __restrict__ counts, const uint4* __restrict__ hev,
                           float* __restrict__ node_out, float* __restrict__ edge_out) {
    int wave = (int)((blockIdx.x * (size_t)blockDim.x + threadIdx.x) >> 6);
    int lane = threadIdx.x & 63;
    if (wave >= NN) return;
    int half = lane >> 5, sl = lane & 31;
    int o = offsets[wave], c = counts[wave];
    float aH0 = 0.f, aH1 = 0.f, aH2 = 0.f, aH3 = 0.f;
    float aE0 = 0.f, aE1 = 0.f, aE2 = 0.f, aE3 = 0.f;
    float4 z = make_float4(0.f, 0.f, 0.f, 0.f);
    uint4 zu = make_uint4(0u, 0u, 0u, 0u);
    int np = (c + 1) >> 1;
    float4 m0 = (half < c) ? meta[o + half] : z;
    uint4 v0 = (half < c) ? hev[(size_t)__float_as_int(m0.x) * 32 + sl] : zu;
    for (int k2 = 0; k2 < np; ++k2) {
        int keN = 2 * (k2 + 1) + half;
        float4 m1 = (keN < c) ? meta[o + keN] : z;
        uint4 v1 = (keN < c) ? hev[(size_t)__float_as_int(m1.x) * 32 + sl] : zu;
        float nn = m0.y, en = m0.z;
        aH0 += __uint_as_float(v0.x << 16) * nn;
        aH1 += __uint_as_float(v0.x & 0xFFFF0000u) * nn;
        aE0 += __uint_as_float(v0.y << 16) * en;
        aE1 += __uint_as_float(v0.y & 0xFFFF0000u) * en;
        aH2 += __uint_as_float(v0.z << 16) * nn;
        aH3 += __uint_as_float(v0.z & 0xFFFF0000u) * nn;
        aE2 += __uint_as_float(v0.w << 16) * en;
        aE3 += __uint_as_float(v0.w & 0xFFFF0000u) * en;
        m0 = m1; v0 = v1;
    }
    // combine the two half-wave partial sums (lane <-> lane+32)
    aH0 += __shfl_xor(aH0, 32); aH1 += __shfl_xor(aH1, 32);
    aH2 += __shfl_xor(aH2, 32); aH3 += __shfl_xor(aH3, 32);
    aE0 += __shfl_xor(aE0, 32); aE1 += __shfl_xor(aE1, 32);
    aE2 += __shfl_xor(aE2, 32); aE3 += __shfl_xor(aE3, 32);
    if (half == 0) {
        float4 rn = { aH0, aH1, aH2, aH3 };
        float4 re = { aE0, aE1, aE2, aE3 };
        *reinterpret_cast<float4*>(node_out + (size_t)wave * 128 + sl * 4) = rn;
        *reinterpret_cast<float4*>(edge_out + (size_t)wave * 128 + sl * 4) = re;
    }
}

// ---------------- finalize variance ----------------
__global__ void finalize_var(const double* __restrict__ acc, float* __restrict__ out_var) {
    if (threadIdx.x == 0 && blockIdx.x == 0) {
        double M = 2.0 * EE;
        double nv = (acc[1] - acc[0] * acc[0] / M) / (M - 1.0);
        double ev = (acc[3] - acc[2] * acc[2] / M) / (M - 1.0);
        out_var[0] = (float)nv;
        out_var[1] = (float)ev;
    }
}

extern "C" void kernel_launch(void* const* d_in, const int* in_sizes, int n_in,
                              void* d_out, int out_size, void* d_ws, size_t ws_size,
                              hipStream_t stream) {
    const float* node_fts = (const float*)d_in[0];
    const float* edge_fts = (const float*)d_in[1];
    const int*   edges    = (const int*)d_in[2];
    const float* W_node   = (const float*)d_in[3];
    const float* W_edge   = (const float*)d_in[4];
    const float* a_node   = (const float*)d_in[5];
    const float* a_edge   = (const float*)d_in[6];
    float* out = (float*)d_out;

    char* w = (char*)d_ws;
    auto alloc = [&](size_t bytes) -> void* {
        void* p = (void*)w;
        w += (bytes + 255) & ~(size_t)255;
        return p;
    };
    unsigned* hevu = (unsigned*)alloc((size_t)NN * 512);        // bf16 interleaved h/e rows
    float* s1    = (float*)alloc(NN * 4);
    float* s2    = (float*)alloc(NN * 4);
    float* t1    = (float*)alloc(NN * 4);
    float* t2e   = (float*)alloc(EE * 4);
    unsigned* rank = (unsigned*)alloc((size_t)2 * EE * 4);
    float4* meta = (float4*)alloc((size_t)2 * EE * 16);
    int*   offsets = (int*)alloc((NN + 1) * 4);
    int*   g       = (int*)alloc(2 * EE * 4);
    int*   bsums   = (int*)alloc(64 * 4);
    float* wn_a1 = (float*)alloc(256 * 4);
    float* wn_a2 = (float*)alloc(256 * 4);
    float* wn_e1 = (float*)alloc(256 * 4);
    float* we_a2 = (float*)alloc(128 * 4);
    unsigned short* Wt_node = (unsigned short*)alloc(256 * 128 * 2);
    unsigned short* Wt_edge = (unsigned short*)alloc(128 * 128 * 2);
    float* nsum   = (float*)alloc(NN * 4);
    float* esum   = (float*)alloc(NN * 4);
    int*   counts = (int*)alloc(NN * 4);
    int*   cursorR = (int*)alloc((size_t)REPS * NN * 4);
    // contiguous zero block: histR (u64), acc (4 doubles)
    char* zb = (char*)alloc((size_t)REPS * NN * 8 + 64);
    unsigned long long* histR = (unsigned long long*)zb;
    double* acc = (double*)(zb + (size_t)REPS * NN * 8);

    const size_t n64 = (size_t)REPS * NN + 8;
    zero_ws<<<(int)((n64 + 255) / 256), 256, 0, stream>>>((unsigned long long*)zb, n64);

    prep<<<64, 256, 0, stream>>>(W_node, W_edge, a_node, a_edge, wn_a1, wn_a2, wn_e1, we_a2,
                                 Wt_node, Wt_edge);

    const int gemm_grid = (NN + 63) / 64;  // 782
    gemm_mfma<256, 0, true><<<gemm_grid, 256, 0, stream>>>(node_fts, Wt_node, wn_a1, wn_a2, wn_e1,
                                                           hevu, s1, s2, t1, NN);
    gemm_mfma<128, 1, false><<<gemm_grid, 256, 0, stream>>>(edge_fts, Wt_edge, nullptr, nullptr,
                                                            we_a2, hevu, nullptr, nullptr, t2e, NN);

    edge_scalar_tail<<<((EE - NN) + 3) / 4, 256, 0, stream>>>(edge_fts, we_a2, t2e);

    attention<<<(2 * EE + 255) / 256, 256, 0, stream>>>(edges, s1, s2, t1, t2e, histR, rank);

    const int nscan = (NN + SCAN_CHUNK - 1) / SCAN_CHUNK;  // 25
    reduce_reps<<<nscan, 256, 0, stream>>>(histR, nsum, esum, counts, bsums);
    scan_bsums<<<1, 64, 0, stream>>>(bsums, nscan);
    scan_final<<<nscan, 256, 0, stream>>>(counts, bsums, histR, offsets, cursorR, g);

    normalize_var<<<(2 * EE + 255) / 256, 256, 0, stream>>>(s1, s2, t1, t2e, nsum, esum, g, edges,
                                                            cursorR, rank, meta, acc);

    accumulate<<<(NN + 3) / 4, 256, 0, stream>>>(meta, offsets, counts, (const uint4*)hevu,
                                                 out, out + (size_t)NN * 128);

    finalize_var<<<1, 64, 0, stream>>>(acc, out + (size_t)2 * NN * 128);
}

// Round 9
// 355.162 us; speedup vs baseline: 1.3231x; 1.0137x over previous
//
#include <hip/hip_runtime.h>
#include <hip/hip_bf16.h>

#define NN 50000
#define EE 400000
#define QSCALE 131072.0f   // 2^17 fixed-point scale for packed histogram
#define SCAN_CHUNK 2048

typedef short bf16x8 __attribute__((ext_vector_type(8)));
typedef float f32x4 __attribute__((ext_vector_type(4)));
typedef float f32x4v __attribute__((ext_vector_type(4)));
typedef float f32x2v __attribute__((ext_vector_type(2)));

__device__ inline unsigned bf16pair(float a, float b) {
    unsigned ua = __float_as_uint(a), ub = __float_as_uint(b);
    ua = (ua + 0x7FFFu + ((ua >> 16) & 1u)) >> 16;
    ub = (ub + 0x7FFFu + ((ub >> 16) & 1u)) >> 16;
    return ua | (ub << 16);
}

// ---------------- fast workspace zero ----------------
__global__ void zero_ws(unsigned long long* __restrict__ p, size_t n64) {
    size_t i = (size_t)blockIdx.x * blockDim.x + threadIdx.x;
    size_t stride = (size_t)gridDim.x * blockDim.x;
    for (; i < n64; i += stride) p[i] = 0ULL;
}

// ---------------- prep: fold a-vectors through W (block 0) + transpose W to bf16 (all) ----------------
__global__ void prep(const float* __restrict__ W_node, const float* __restrict__ W_edge,
                     const float* __restrict__ a_node, const float* __restrict__ a_edge,
                     float* wn_a1, float* wn_a2, float* wn_e1, float* we_a2,
                     unsigned short* __restrict__ Wt_node, unsigned short* __restrict__ Wt_edge) {
    int t = threadIdx.x;
    if (blockIdx.x == 0) {
        if (t < 256) {
            float x1 = 0.f, x2 = 0.f, x3 = 0.f;
            for (int j = 0; j < 128; ++j) {
                float w = W_node[t * 128 + j];
                x1 += w * a_node[j];
                x2 += w * a_node[128 + j];
                x3 += w * a_edge[j];
            }
            wn_a1[t] = x1; wn_a2[t] = x2; wn_e1[t] = x3;
        }
        if (t < 128) {
            float x = 0.f;
            for (int j = 0; j < 128; ++j) x += W_edge[t * 128 + j] * a_edge[128 + j];
            we_a2[t] = x;
        }
    }
    int gid = blockIdx.x * blockDim.x + t;
    int nth = gridDim.x * blockDim.x;
    for (int idx = gid; idx < 256 * 128; idx += nth) {
        int r = idx >> 7, c = idx & 127;
        unsigned u = __float_as_uint(W_node[idx]);
        u = (u + 0x7FFFu + ((u >> 16) & 1u)) >> 16;
        Wt_node[c * 256 + r] = (unsigned short)u;
    }
    for (int idx = gid; idx < 128 * 128; idx += nth) {
        int r = idx >> 7, c = idx & 127;
        unsigned u = __float_as_uint(W_edge[idx]);
        u = (u + 0x7FFFu + ((u >> 16) & 1u)) >> 16;
        Wt_edge[c * 128 + r] = (unsigned short)u;
    }
}

// ---------------- fused MFMA bf16 GEMM (h + e + 4 scalar dots), full-line hev writes ----------------
__global__ __launch_bounds__(256) void gemm_fused(const float* __restrict__ NF,
                                                  const float* __restrict__ EF,
                                                  const unsigned short* __restrict__ WtN,
                                                  const unsigned short* __restrict__ WtE,
                                                  const float* __restrict__ w1,
                                                  const float* __restrict__ w2,
                                                  const float* __restrict__ w3,
                                                  const float* __restrict__ w4,
                                                  unsigned* __restrict__ hevu,
                                                  float* __restrict__ s1, float* __restrict__ s2,
                                                  float* __restrict__ t1, float* __restrict__ t2e,
                                                  int M) {
    int t = threadIdx.x;
    int wv = t >> 6, l = t & 63;
    int rl = l & 15, kg = l >> 4;
    int wrow0 = blockIdx.x * 64 + wv * 16;
    int gr = wrow0 + rl;
    int ar = gr < M ? gr : M - 1;
    const float* ArowN = NF + (size_t)ar * 256;
    const float* ArowE = EF + (size_t)ar * 128;
    f32x4 accH[8], accE[8];
#pragma unroll
    for (int i = 0; i < 8; ++i) { accH[i] = (f32x4){0.f,0.f,0.f,0.f}; accE[i] = (f32x4){0.f,0.f,0.f,0.f}; }
    float p1 = 0.f, p2 = 0.f, p3 = 0.f, p4 = 0.f;
    // ---- node part: K=256 ----
    for (int k0 = 0; k0 < 256; k0 += 32) {
        int kb = k0 + kg * 8;
        f32x4v alo = __builtin_nontemporal_load(reinterpret_cast<const f32x4v*>(ArowN + kb));
        f32x4v ahi = __builtin_nontemporal_load(reinterpret_cast<const f32x4v*>(ArowN + kb + 4));
        union { unsigned u[4]; bf16x8 v; } af;
        af.u[0] = bf16pair(alo.x, alo.y);
        af.u[1] = bf16pair(alo.z, alo.w);
        af.u[2] = bf16pair(ahi.x, ahi.y);
        af.u[3] = bf16pair(ahi.z, ahi.w);
        {
            float4 wl = *reinterpret_cast<const float4*>(w1 + kb);
            float4 wh = *reinterpret_cast<const float4*>(w1 + kb + 4);
            p1 += alo.x*wl.x + alo.y*wl.y + alo.z*wl.z + alo.w*wl.w
                + ahi.x*wh.x + ahi.y*wh.y + ahi.z*wh.z + ahi.w*wh.w;
        }
        {
            float4 wl = *reinterpret_cast<const float4*>(w2 + kb);
            float4 wh = *reinterpret_cast<const float4*>(w2 + kb + 4);
            p2 += alo.x*wl.x + alo.y*wl.y + alo.z*wl.z + alo.w*wl.w
                + ahi.x*wh.x + ahi.y*wh.y + ahi.z*wh.z + ahi.w*wh.w;
        }
        {
            float4 wl = *reinterpret_cast<const float4*>(w3 + kb);
            float4 wh = *reinterpret_cast<const float4*>(w3 + kb + 4);
            p3 += alo.x*wl.x + alo.y*wl.y + alo.z*wl.z + alo.w*wl.w
                + ahi.x*wh.x + ahi.y*wh.y + ahi.z*wh.z + ahi.w*wh.w;
        }
#pragma unroll
        for (int nt = 0; nt < 8; ++nt) {
            union { unsigned u[4]; bf16x8 v; } bf;
            const unsigned* bp = reinterpret_cast<const unsigned*>(WtN + (size_t)(rl + 16*nt) * 256 + kb);
            bf.u[0] = bp[0]; bf.u[1] = bp[1]; bf.u[2] = bp[2]; bf.u[3] = bp[3];
            accH[nt] = __builtin_amdgcn_mfma_f32_16x16x32_bf16(af.v, bf.v, accH[nt], 0, 0, 0);
        }
    }
    // ---- edge part: K=128 ----
    for (int k0 = 0; k0 < 128; k0 += 32) {
        int kb = k0 + kg * 8;
        f32x4v alo = __builtin_nontemporal_load(reinterpret_cast<const f32x4v*>(ArowE + kb));
        f32x4v ahi = __builtin_nontemporal_load(reinterpret_cast<const f32x4v*>(ArowE + kb + 4));
        union { unsigned u[4]; bf16x8 v; } af;
        af.u[0] = bf16pair(alo.x, alo.y);
        af.u[1] = bf16pair(alo.z, alo.w);
        af.u[2] = bf16pair(ahi.x, ahi.y);
        af.u[3] = bf16pair(ahi.z, ahi.w);
        {
            float4 wl = *reinterpret_cast<const float4*>(w4 + kb);
            float4 wh = *reinterpret_cast<const float4*>(w4 + kb + 4);
            p4 += alo.x*wl.x + alo.y*wl.y + alo.z*wl.z + alo.w*wl.w
                + ahi.x*wh.x + ahi.y*wh.y + ahi.z*wh.z + ahi.w*wh.w;
        }
#pragma unroll
        for (int nt = 0; nt < 8; ++nt) {
            union { unsigned u[4]; bf16x8 v; } bf;
            const unsigned* bp = reinterpret_cast<const unsigned*>(WtE + (size_t)(rl + 16*nt) * 128 + kb);
            bf.u[0] = bp[0]; bf.u[1] = bp[1]; bf.u[2] = bp[2]; bf.u[3] = bp[3];
            accE[nt] = __builtin_amdgcn_mfma_f32_16x16x32_bf16(af.v, bf.v, accE[nt], 0, 0, 0);
        }
    }
    // fused scalar outputs
    p1 += __shfl_xor(p1, 16); p1 += __shfl_xor(p1, 32);
    p2 += __shfl_xor(p2, 16); p2 += __shfl_xor(p2, 32);
    p3 += __shfl_xor(p3, 16); p3 += __shfl_xor(p3, 32);
    p4 += __shfl_xor(p4, 16); p4 += __shfl_xor(p4, 32);
    if (l < 16 && gr < M) { s1[gr] = p1; s2[gr] = p2; t1[gr] = p3; t2e[gr] = p4; }
    // epilogue: full uint2 (h-pair, e-pair) writes
#pragma unroll
    for (int nt = 0; nt < 8; ++nt) {
#pragma unroll
        for (int reg = 0; reg < 4; ++reg) {
            float hm = accH[nt][reg];
            float ho = __shfl_xor(hm, 1);
            float em = accE[nt][reg];
            float eo = __shfl_xor(em, 1);
            int orow = wrow0 + kg * 4 + reg;
            if (orow < M) {
                int col = rl + 16 * nt;
                if (!(l & 1)) {
                    if (reg < 2) {
                        uint2 wv2 = { bf16pair(hm, ho), bf16pair(em, eo) };
                        *reinterpret_cast<uint2*>(hevu + (size_t)orow * 128 + col) = wv2;
                    }
                } else {
                    if (reg >= 2) {
                        uint2 wv2 = { bf16pair(ho, hm), bf16pair(eo, em) };
                        *reinterpret_cast<uint2*>(hevu + (size_t)orow * 128 + (col - 1)) = wv2;
                    }
                }
            }
        }
    }
}

// ---------------- per-edge scalar t2e for rows [NN, EE) ----------------
__global__ void edge_scalar_tail(const float* __restrict__ EF, const float* __restrict__ w,
                                 float* __restrict__ t2e) {
    int wave = NN + (int)((blockIdx.x * (size_t)blockDim.x + threadIdx.x) >> 6);
    int lane = threadIdx.x & 63;
    if (wave >= EE) return;
    f32x2v v = __builtin_nontemporal_load(reinterpret_cast<const f32x2v*>(EF + (size_t)wave * 128 + lane * 2));
    float a = v.x * w[lane * 2] + v.y * w[lane * 2 + 1];
    for (int off = 32; off; off >>= 1) a += __shfl_down(a, off);
    if (lane == 0) t2e[wave] = a;
}

// ---------------- per-edge attention: ONE packed u64 atomic per edge-end ----------------
__global__ void attention(const int* __restrict__ edges, const float* __restrict__ s1,
                          const float* __restrict__ s2, const float* __restrict__ t1,
                          const float* __restrict__ t2e, unsigned long long* __restrict__ hist,
                          unsigned* __restrict__ rank) {
    int i = blockIdx.x * blockDim.x + threadIdx.x;
    if (i >= 2 * EE) return;
    int s, d, j;
    if (i < EE) { j = i; int2 p = *reinterpret_cast<const int2*>(edges + 2 * j); s = p.x; d = p.y; }
    else        { j = i - EE; int2 p = *reinterpret_cast<const int2*>(edges + 2 * j); s = p.y; d = p.x; }
    float xn = s1[s] + s2[d];
    xn = xn >= 0.f ? xn : 0.2f * xn;
    xn = fminf(fmaxf(xn, -2.f), 2.f);
    float na = __expf(xn);
    float xe = t1[s] + t2e[j];
    xe = xe >= 0.f ? xe : 0.2f * xe;
    xe = fminf(fmaxf(xe, -2.f), 2.f);
    float ea = __expf(xe);
    unsigned qn = __float2uint_rn(na * QSCALE);
    unsigned qe = __float2uint_rn(ea * QSCALE);
    unsigned long long pk = (1ULL << 56) | ((unsigned long long)qn << 28) | (unsigned long long)qe;
    unsigned long long old = atomicAdd(&hist[s], pk);
    rank[i] = (unsigned)(old >> 56);
}

// ---------------- unpack hist + per-scan-chunk count sums ----------------
__global__ void reduce_unpack(const unsigned long long* __restrict__ hist, float* __restrict__ nsum,
                              float* __restrict__ esum, int* __restrict__ counts,
                              int* __restrict__ bsums) {
    __shared__ int sdata[256];
    int b = blockIdx.x, t = threadIdx.x;
    int base = b * SCAN_CHUNK;
    int csum = 0;
    for (int j = 0; j < 8; ++j) {
        int idx = base + j * 256 + t;
        if (idx < NN) {
            unsigned long long h = hist[idx];
            int c = (int)(h >> 56);
            counts[idx] = c;
            nsum[idx] = (float)((h >> 28) & 0x0FFFFFFFULL) * (1.0f / QSCALE);
            esum[idx] = (float)(h & 0x0FFFFFFFULL) * (1.0f / QSCALE);
            csum += c;
        }
    }
    sdata[t] = csum; __syncthreads();
    for (int off = 128; off; off >>= 1) { if (t < off) sdata[t] += sdata[t + off]; __syncthreads(); }
    if (t == 0) bsums[b] = sdata[0];
}

__global__ void scan_bsums(int* __restrict__ bsums, int nb) {
    if (threadIdx.x == 0 && blockIdx.x == 0) {
        int run = 0;
        for (int i = 0; i < nb; ++i) { int v = bsums[i]; bsums[i] = run; run += v; }
    }
}

// ---------------- final scan: offsets + position->node map g ----------------
__global__ void scan_final(const int* __restrict__ counts, const int* __restrict__ bsums,
                           int* __restrict__ offsets, int* __restrict__ g) {
    __shared__ int sdata[256];
    int b = blockIdx.x, t = threadIdx.x;
    int base = b * SCAN_CHUNK + t * 8;
    int loc[8]; int s = 0;
    for (int j = 0; j < 8; ++j) { int idx = base + j; int v = (idx < NN) ? counts[idx] : 0; loc[j] = v; s += v; }
    sdata[t] = s; __syncthreads();
    for (int off = 1; off < 256; off <<= 1) {
        int v = (t >= off) ? sdata[t - off] : 0;
        __syncthreads();
        sdata[t] += v;
        __syncthreads();
    }
    int run = sdata[t] - s + bsums[b];
    for (int j = 0; j < 8; ++j) {
        int idx = base + j;
        if (idx < NN) {
            offsets[idx] = run;
            for (int k = 0; k < loc[j]; ++k) g[run + k] = idx;
            run += loc[j];
        }
    }
}

// ---------------- normalize (recompute exp) + atomic-free CSR meta scatter + variance ----------------
__global__ void normalize_var(const float* __restrict__ s1, const float* __restrict__ s2,
                              const float* __restrict__ t1, const float* __restrict__ t2e,
                              const float* __restrict__ nsum, const float* __restrict__ esum,
                              const int* __restrict__ g, const int* __restrict__ edges,
                              const int* __restrict__ offsets, const unsigned* __restrict__ rank,
                              float4* __restrict__ meta, double* __restrict__ acc) {
    int i = blockIdx.x * blockDim.x + threadIdx.x;
    float nn = 0.f, en = 0.f;
    if (i < 2 * EE) {
        int s, d, j;
        if (i < EE) { j = i; int2 p = *reinterpret_cast<const int2*>(edges + 2 * j); s = p.x; d = p.y; }
        else        { j = i - EE; int2 p = *reinterpret_cast<const int2*>(edges + 2 * j); s = p.y; d = p.x; }
        float xn = s1[s] + s2[d];
        xn = xn >= 0.f ? xn : 0.2f * xn;
        xn = fminf(fmaxf(xn, -2.f), 2.f);
        float na = __expf(xn);
        float xe = t1[s] + t2e[j];
        xe = xe >= 0.f ? xe : 0.2f * xe;
        xe = fminf(fmaxf(xe, -2.f), 2.f);
        float ea = __expf(xe);
        int gi = g[i];
        nn = na / nsum[gi];
        en = ea / esum[gi];
        int slot = offsets[s] + (int)rank[i];
        meta[slot] = make_float4(__int_as_float(d), nn, en, 0.f);
    }
    double v[4] = { (double)nn, (double)nn * nn, (double)en, (double)en * en };
    __shared__ double sd[4][4];
    int lane = threadIdx.x & 63, wv = threadIdx.x >> 6;
#pragma unroll
    for (int q = 0; q < 4; ++q) {
        double x = v[q];
        for (int off = 32; off; off >>= 1) x += __shfl_down(x, off);
        if (lane == 0) sd[q][wv] = x;
    }
    __syncthreads();
    if (threadIdx.x < 4) {
        double x = sd[threadIdx.x][0] + sd[threadIdx.x][1] + sd[threadIdx.x][2] + sd[threadIdx.x][3];
        atomicAdd(&acc[threadIdx.x], x);
    }
}

// ---------------- CSR accumulate: wave per node, 2 edges/trip, depth-2 gather pipeline ----------------
__global__ void accumulate(const float4* __restrict__ meta, const int* __restrict__ offsets,
                           const int* __restrict__ counts, const uint4* __restrict__ hev,
                           float* __restrict__ node_out, float* __restrict__ edge_out) {
    int wave = (int)((blockIdx.x * (size_t)blockDim.x + threadIdx.x) >> 6);
    int lane = threadIdx.x & 63;
    if (wave >= NN) return;
    int half = lane >> 5, sl = lane & 31;
    int o = offsets[wave], c = counts[wave];
    float aH0 = 0.f, aH1 = 0.f, aH2 = 0.f, aH3 = 0.f;
    float aE0 = 0.f, aE1 = 0.f, aE2 = 0.f, aE3 = 0.f;
    float4 z = make_float4(0.f, 0.f, 0.f, 0.f);
    uint4 zu = make_uint4(0u, 0u, 0u, 0u);
    int np = (c + 1) >> 1;
    // my edge sequence: e_k = 2k + half
    int e0 = half, e1 = 2 + half, e2i = 4 + half;
    float4 m0 = (e0 < c) ? meta[o + e0] : z;
    float4 m1 = (e1 < c) ? meta[o + e1] : z;
    float4 m2 = (e2i < c) ? meta[o + e2i] : z;
    uint4 v0 = (e0 < c) ? hev[(size_t)__float_as_int(m0.x) * 32 + sl] : zu;
    uint4 v1 = (e1 < c) ? hev[(size_t)__float_as_int(m1.x) * 32 + sl] : zu;
    for (int k = 0; k < np; ++k) {
        int ep2 = 2 * (k + 2) + half, ep3 = 2 * (k + 3) + half;
        uint4 v2 = (ep2 < c) ? hev[(size_t)__float_as_int(m2.x) * 32 + sl] : zu;
        float4 m3 = (ep3 < c) ? meta[o + ep3] : z;
        float nn = m0.y, en = m0.z;
        aH0 += __uint_as_float(v0.x << 16) * nn;
        aH1 += __uint_as_float(v0.x & 0xFFFF0000u) * nn;
        aE0 += __uint_as_float(v0.y << 16) * en;
        aE1 += __uint_as_float(v0.y & 0xFFFF0000u) * en;
        aH2 += __uint_as_float(v0.z << 16) * nn;
        aH3 += __uint_as_float(v0.z & 0xFFFF0000u) * nn;
        aE2 += __uint_as_float(v0.w << 16) * en;
        aE3 += __uint_as_float(v0.w & 0xFFFF0000u) * en;
        m0 = m1; m1 = m2; m2 = m3; v0 = v1; v1 = v2;
    }
    aH0 += __shfl_xor(aH0, 32); aH1 += __shfl_xor(aH1, 32);
    aH2 += __shfl_xor(aH2, 32); aH3 += __shfl_xor(aH3, 32);
    aE0 += __shfl_xor(aE0, 32); aE1 += __shfl_xor(aE1, 32);
    aE2 += __shfl_xor(aE2, 32); aE3 += __shfl_xor(aE3, 32);
    if (half == 0) {
        f32x4v rn = { aH0, aH1, aH2, aH3 };
        f32x4v re = { aE0, aE1, aE2, aE3 };
        __builtin_nontemporal_store(rn, reinterpret_cast<f32x4v*>(node_out + (size_t)wave * 128 + sl * 4));
        __builtin_nontemporal_store(re, reinterpret_cast<f32x4v*>(edge_out + (size_t)wave * 128 + sl * 4));
    }
}

// ---------------- finalize variance ----------------
__global__ void finalize_var(const double* __restrict__ acc, float* __restrict__ out_var) {
    if (threadIdx.x == 0 && blockIdx.x == 0) {
        double M = 2.0 * EE;
        double nv = (acc[1] - acc[0] * acc[0] / M) / (M - 1.0);
        double ev = (acc[3] - acc[2] * acc[2] / M) / (M - 1.0);
        out_var[0] = (float)nv;
        out_var[1] = (float)ev;
    }
}

extern "C" void kernel_launch(void* const* d_in, const int* in_sizes, int n_in,
                              void* d_out, int out_size, void* d_ws, size_t ws_size,
                              hipStream_t stream) {
    const float* node_fts = (const float*)d_in[0];
    const float* edge_fts = (const float*)d_in[1];
    const int*   edges    = (const int*)d_in[2];
    const float* W_node   = (const float*)d_in[3];
    const float* W_edge   = (const float*)d_in[4];
    const float* a_node   = (const float*)d_in[5];
    const float* a_edge   = (const float*)d_in[6];
    float* out = (float*)d_out;

    char* w = (char*)d_ws;
    auto alloc = [&](size_t bytes) -> void* {
        void* p = (void*)w;
        w += (bytes + 255) & ~(size_t)255;
        return p;
    };
    unsigned* hevu = (unsigned*)alloc((size_t)NN * 512);        // bf16 interleaved h/e rows
    float* s1    = (float*)alloc(NN * 4);
    float* s2    = (float*)alloc(NN * 4);
    float* t1    = (float*)alloc(NN * 4);
    float* t2e   = (float*)alloc(EE * 4);
    unsigned* rank = (unsigned*)alloc((size_t)2 * EE * 4);
    float4* meta = (float4*)alloc((size_t)2 * EE * 16);
    int*   offsets = (int*)alloc((NN + 1) * 4);
    int*   g       = (int*)alloc(2 * EE * 4);
    int*   bsums   = (int*)alloc(64 * 4);
    float* wn_a1 = (float*)alloc(256 * 4);
    float* wn_a2 = (float*)alloc(256 * 4);
    float* wn_e1 = (float*)alloc(256 * 4);
    float* we_a2 = (float*)alloc(128 * 4);
    unsigned short* Wt_node = (unsigned short*)alloc(256 * 128 * 2);
    unsigned short* Wt_edge = (unsigned short*)alloc(128 * 128 * 2);
    float* nsum   = (float*)alloc(NN * 4);
    float* esum   = (float*)alloc(NN * 4);
    int*   counts = (int*)alloc(NN * 4);
    // contiguous zero block: hist (u64), acc (4 doubles)
    char* zb = (char*)alloc((size_t)NN * 8 + 64);
    unsigned long long* hist = (unsigned long long*)zb;
    double* acc = (double*)(zb + (size_t)NN * 8);

    const size_t n64 = (size_t)NN + 8;
    zero_ws<<<(int)((n64 + 255) / 256), 256, 0, stream>>>((unsigned long long*)zb, n64);

    prep<<<64, 256, 0, stream>>>(W_node, W_edge, a_node, a_edge, wn_a1, wn_a2, wn_e1, we_a2,
                                 Wt_node, Wt_edge);

    const int gemm_grid = (NN + 63) / 64;  // 782
    gemm_fused<<<gemm_grid, 256, 0, stream>>>(node_fts, edge_fts, Wt_node, Wt_edge,
                                              wn_a1, wn_a2, wn_e1, we_a2,
                                              hevu, s1, s2, t1, t2e, NN);

    edge_scalar_tail<<<((EE - NN) + 3) / 4, 256, 0, stream>>>(edge_fts, we_a2, t2e);

    attention<<<(2 * EE + 255) / 256, 256, 0, stream>>>(edges, s1, s2, t1, t2e, hist, rank);

    const int nscan = (NN + SCAN_CHUNK - 1) / SCAN_CHUNK;  // 25
    reduce_unpack<<<nscan, 256, 0, stream>>>(hist, nsum, esum, counts, bsums);
    scan_bsums<<<1, 64, 0, stream>>>(bsums, nscan);
    scan_final<<<nscan, 256, 0, stream>>>(counts, bsums, offsets, g);

    normalize_var<<<(2 * EE + 255) / 256, 256, 0, stream>>>(s1, s2, t1, t2e, nsum, esum, g, edges,
                                                            offsets, rank, meta, acc);

    accumulate<<<(NN + 3) / 4, 256, 0, stream>>>(meta, offsets, counts, (const uint4*)hevu,
                                                 out, out + (size_t)NN * 128);

    finalize_var<<<1, 64, 0, stream>>>(acc, out + (size_t)2 * NN * 128);
}